// Round 1
// 5821.009 us; speedup vs baseline: 1.8798x; 1.8798x over previous
//
#include <hip/hip_runtime.h>
#include <math.h>

// EMMA_38792144617759 v9 — v8 (passed, 10.9ms) with ONE change class: k2's DEQ
// weight slices (W1ZT cols, W2T cols) become LDS-resident (loaded once per WG in
// the preamble, 129-float4 padded stride), and the small cross-WG activations
// (z, t-half) are staged global->LDS with coalesced loads at phase start.
// Rationale: rocprof showed VALUBusy 3.8%, HBM 2.8%, 1 wave/SIMD — phases are
// latency-bound on re-streaming identical 64KB weight slices from LLC every
// phase (gbar's agent-acquire buffer_inv evicts L2 each phase). LDS is immune
// to the invalidation. Sync structure / barrier count / atomics verbatim v8.

#define NGRP 8
#define WPG  32

// ---- workspace float offsets (wsF = d_ws + 16KB; first 16KB is int region) ----
#define OF_SCALE  0
#define OF_DFAC   32
#define OF_RNV    64
#define OF_TOPW   1088
#define OF_SCORES 1600      // 32*4096
#define OF_Z      132672    // 2*32*512 (double-buffered z)
#define OF_T      165440    // 32*1024
#define OF_CP     198208    // 32*1024
#define OF_G      230976    // 32*512
#define OF_TAU    247360    // 32*512
#define OF_H      263744    // 32*512
#define OF_ZS     280128    // 32*512
#define OF_HS     296512    // 32*512
#define OF_M      312896    // 4096*256
// transposed weight copies (filled by emma_tr before k2):
#define OF_W1ZT   1361472   // [1024 c][512 k]  = u_W1[k][c], k<512
#define OF_W1XT   1885760   // [1024 c][256 k]  = u_W1[512+k][c]
#define OF_W2T    2147904   // [512 c][1024 k]  = u_W2[k][c]
#define OF_LWIT   2672192   // [512 c][512 k]   = l_Wi[k][c]
#define OF_LWHT   2934336   // [512 c][512 k]   = l_Wh[k][c]
#define OF_LWTIT  3196480   // [512 c][512 k]   = l_Wti[k][c]
#define OF_LWTHT  3458624   // [512 c][512 k]   = l_Wth[k][c]
// end: 3720768 floats (~14.2MB) + 16KB ints
// wsI: [0..2048) barrier flags region (g*32+w used), [2048..2560) top_i

__device__ __forceinline__ float softplusf_(float x){ return x > 20.f ? x : log1pf(expf(x)); }

// Fence barrier (PROVEN in R4).
__device__ __forceinline__ void gbar(int* flags, int w, int& epoch){
  __syncthreads();
  epoch++;
  if (threadIdx.x == 0){
    __builtin_amdgcn_fence(__ATOMIC_RELEASE, "agent");
    __hip_atomic_store(&flags[w], epoch, __ATOMIC_RELAXED, __HIP_MEMORY_SCOPE_AGENT);
  }
  if (threadIdx.x < 32){
    while (__hip_atomic_load(&flags[threadIdx.x], __ATOMIC_RELAXED,
                             __HIP_MEMORY_SCOPE_AGENT) < epoch)
      __builtin_amdgcn_s_sleep(1);
    __builtin_amdgcn_fence(__ATOMIC_ACQUIRE, "agent");
  }
  __syncthreads();
}

// ---------------- kernel 0: generic row-major -> col-major transpose ----------------
__global__ void __launch_bounds__(256) emma_tr(const float* src, float* dst,
                                               int shift, int total)
{
  const int R = total >> shift;
  const int cmask = (1 << shift) - 1;
  for (int idx = blockIdx.x*256 + threadIdx.x; idx < total; idx += gridDim.x*256){
    int r = idx >> shift, c = idx & cmask;
    dst[(size_t)c * R + r] = src[idx];
  }
}

// ---------------- kernel 1a: scores, M zero, value-row norms, misc (v8 verbatim) ----------------
__global__ void __launch_bounds__(256) emma_k1a(
    const int* key_ids, const int* write_pos,
    const float* key_W, const float* value_W, const float* slot_keys,
    const float* lsr, int* wsI, float* wsF)
{
  const int wg = blockIdx.x, tid = threadIdx.x;
  if (wg < 256) {
    const int b = wg >> 3, chunk = wg & 7;
    __shared__ __align__(16) float s_kv[256];
    __shared__ float red[256];
    float v = key_W[key_ids[b]*256 + tid];
    red[tid] = v*v; __syncthreads();
    for (int st=128; st; st>>=1){ if (tid<st) red[tid]+=red[tid+st]; __syncthreads(); }
    float inv = 1.f/fmaxf(sqrtf(red[0]), 1e-12f);
    s_kv[tid] = v*inv;
    __syncthreads();
    const int lane = tid & 63, wv = tid >> 6;
    float4 kv4 = *(const float4*)(s_kv + lane*4);
    for (int slot = chunk*512 + wv; slot < chunk*512 + 512; slot += 4){
      float4 sk = *(const float4*)(slot_keys + (size_t)slot*256 + lane*4);
      float p = kv4.x*sk.x + kv4.y*sk.y + kv4.z*sk.z + kv4.w*sk.w;
      #pragma unroll
      for (int m=32;m;m>>=1) p += __shfl_xor(p, m, 64);
      if (lane==0) wsF[OF_SCORES + b*4096 + slot] = p;
    }
  } else if (wg < 320) {
    const int j = wg - 256;
    for (int i=tid;i<16384;i+=256) wsF[OF_M + j*16384 + i] = 0.f;
  } else if (wg < 324) {
    const int row = (wg-320)*256 + tid;
    float ss=0.f; const float* r = value_W + (size_t)row*256;
    for (int k=0;k<256;k++){ float x=r[k]; ss += x*x; }
    wsF[OF_RNV + row] = 1.f/fmaxf(sqrtf(ss), 1e-12f);
  } else {
    for (int i=tid;i<2048;i+=256) wsI[i]=0;
    __shared__ int pres[32];
    if (tid<32){ int p=0; for (int bb=0;bb<32;bb++) if (write_pos[bb]==tid) p=1; pres[tid]=p; }
    __syncthreads();
    if (tid<32){
      int wp = write_pos[tid]; float f=1.f;
      for (int s=wp+1;s<32;s++) if (pres[s]) f *= 0.997f;
      wsF[OF_DFAC + tid] = f;
    }
    if (tid==0) wsF[OF_SCALE] = softplusf_(lsr[0]) + 1e-3f;
  }
}

// ---------------- kernel 1b: exact top-16 + softmax (v8 verbatim) ----------------
__global__ void __launch_bounds__(256) emma_k1b(int* wsI, float* wsF)
{
  const int b = blockIdx.x, tid = threadIdx.x;
  __shared__ float s_sc[4096];
  __shared__ float s_rv[256]; __shared__ int s_ri[256];
  __shared__ float s_tv[16];
  for (int n=tid;n<4096;n+=256) s_sc[n] = wsF[OF_SCORES + b*4096 + n];
  __syncthreads();
  for (int j=0;j<16;j++){
    float bv = -3.0e38f; int bi = 0x7fffffff;
    for (int n=tid;n<4096;n+=256){
      float v = s_sc[n];
      if (v > bv || (v == bv && n < bi)) { bv=v; bi=n; }
    }
    s_rv[tid]=bv; s_ri[tid]=bi; __syncthreads();
    for (int st=128; st; st>>=1){
      if (tid<st){
        float v2=s_rv[tid+st]; int i2=s_ri[tid+st];
        if (v2 > s_rv[tid] || (v2==s_rv[tid] && i2 < s_ri[tid])) { s_rv[tid]=v2; s_ri[tid]=i2; }
      }
      __syncthreads();
    }
    if (tid==0){
      s_tv[j] = s_rv[0];
      wsI[2048 + b*16 + j] = s_ri[0];
      s_sc[s_ri[0]] = -3.0e38f;
    }
    __syncthreads();
  }
  if (tid==0){
    float mx = s_tv[0], sum=0.f, w[16];
    for (int j=0;j<16;j++){ w[j]=expf(s_tv[j]-mx); sum+=w[j]; }
    for (int j=0;j<16;j++) wsF[OF_TOPW + b*16 + j] = w[j]/sum;
  }
}

// ---------------- kernel 2: persistent trajectory (v8 structure; LDS-resident DEQ weights) ----------------
__global__ void __launch_bounds__(256, 1) emma_k2(
    const int* tokens, const int* write_pos,
    const float* embed_W, const float* u_b1, const float* u_b2,
    const float* l_b, const float* l_bt, const float* h0,
    int* wsI, float* wsF)
{
  const int g = blockIdx.x & 7;
  const int w = blockIdx.x >> 3;
  const int tid = threadIdx.x;
  int* flags = wsI + g*32;
  int epoch = 0;

  float* Z  = wsF + OF_Z;
  float* T  = wsF + OF_T;
  float* CP = wsF + OF_CP;
  float* G  = wsF + OF_G;
  float* TA = wsF + OF_TAU;
  float* H  = wsF + OF_H;
  float* ZS = wsF + OF_ZS;
  float* HS = wsF + OF_HS;

  // LDS: per-WG weight slices (129-f4 padded col stride => 4-way, not 32-way,
  // bank aliasing on the col-major ds_read_b128s) + activation staging buffers.
  // 32*129*16*2 + 2048*4*2 = 148,480 B < 160 KiB.
  __shared__ __align__(16) float4 ldsA[32*129];   // W1ZT cols [w*32, w*32+32)
  __shared__ __align__(16) float4 ldsB[32*129];   // W2T cols [(w&15)*32,+32), k-half (w>>4)
  __shared__ __align__(16) float zstage[2048];    // this group's z [4][512]
  __shared__ __align__(16) float tstage[2048];    // this group's t-half [4][512]

  // ---- stage per-WG DEQ weight slices into LDS (once) ----
  {
    const float* gA = wsF + OF_W1ZT + (size_t)(w*32)*512;
    const float* gB = wsF + OF_W2T  + (size_t)((w&15)*32)*1024 + (size_t)(w>>4)*512;
    for (int idx4 = tid; idx4 < 4096; idx4 += 256){
      int ci = idx4 >> 7, j = idx4 & 127;
      ldsA[ci*129 + j] = *(const float4*)(gA + (size_t)ci*512  + 4*j);
      ldsB[ci*129 + j] = *(const float4*)(gB + (size_t)ci*1024 + 4*j);
    }
  }

  // per-thread loop-invariant constants
  const int rA  = tid >> 5;            // valid for tid<128 phases
  const int bA  = g*4 + (rA & 3);
  const int ciA = tid & 31;
  const int cA  = w*32 + ciA;          // phase A output col
  const int c2B = (w&15)*32 + ciA;     // phase B output col
  float b2half = 0.f; int znr = 0, znc = 0;
  if (tid < 64){ int idx = w*64 + tid; znr = idx>>9; znc = idx&511; b2half = 0.5f*u_b2[znc]; }

  // ---- preamble: z=0, h=h0 | c_pre for step 0 (v8 verbatim) ----
  if (w < 16) {
    int idx = w*256 + tid;
    if (idx < 2048) { int r=idx>>9, c=idx&511; Z[(g*4+r)*512 + c] = 0.f; }
    else { int i2=idx-2048; int r=i2>>9, c=i2&511; H[(g*4+r)*512 + c] = h0[c]; }
  } else {
    int r = tid>>6, b = g*4+r;
    int c = (w-16)*64 + (tid&63);
    int tok = tokens[b*64 + 0];
    const float* xr = embed_W + (size_t)tok*256;
    const float* wc = wsF + OF_W1XT + (size_t)c*256;
    float a0=0,a1=0,a2=0,a3=0;
    #pragma unroll 4
    for (int k=0;k<256;k+=4){
      float4 xv = *(const float4*)(xr + k);
      float4 wv = *(const float4*)(wc + k);
      a0 += xv.x*wv.x; a1 += xv.y*wv.y; a2 += xv.z*wv.z; a3 += xv.w*wv.w;
    }
    CP[b*1024 + c] = u_b1[c] + ((a0+a1)+(a2+a3));
  }
  gbar(flags, w, epoch);

  for (int s=0;s<32;s++){
    // CP for this step is fixed across the 8 DEQ iters — hoist to a register.
    float cpv = (tid < 128) ? CP[bA*1024 + cA] : 0.f;
    for (int i=0;i<8;i++){
      float* zc = Z + (i&1)*16384;
      float* zn = Z + ((i&1)^1)*16384;
      // stage this group's z (8KB) global->LDS, coalesced, one latency exposure
      {
        int ii = tid;
        *(float4*)(zstage + ii*4) = *(const float4*)(zc + g*2048 + ii*4);
        ii = 256 + tid;
        *(float4*)(zstage + ii*4) = *(const float4*)(zc + g*2048 + ii*4);
      }
      __syncthreads();
      // ---- phase A: t = tanh(z@W1z + c_pre); also pre-bias z_next
      if (tid < 128) {
        const float4* wc4 = ldsA + ciA*129;
        const float*  zr  = zstage + rA*512;
        float a0=0,a1=0,a2=0,a3=0;
        #pragma unroll 8
        for (int j=0;j<128;j++){
          float4 wv = wc4[j];
          float4 zv = *(const float4*)(zr + 4*j);
          a0 += zv.x*wv.x; a1 += zv.y*wv.y; a2 += zv.z*wv.z; a3 += zv.w*wv.w;
        }
        T[bA*1024 + cA] = tanhf(cpv + (a0+a1)+(a2+a3));
      }
      if (tid < 64) {
        zn[(g*4+znr)*512 + znc] = zstage[znr*512 + znc] + b2half;
      }
      gbar(flags, w, epoch);
      // stage this group's t k-half (8KB) global->LDS
      {
        int ii = tid; int r = ii>>7, j = ii&127;
        *(float4*)(tstage + r*512 + 4*j) =
            *(const float4*)(T + (size_t)(g*4+r)*1024 + (size_t)(w>>4)*512 + 4*j);
        ii = 256 + tid; r = ii>>7; j = ii&127;
        *(float4*)(tstage + r*512 + 4*j) =
            *(const float4*)(T + (size_t)(g*4+r)*1024 + (size_t)(w>>4)*512 + 4*j);
      }
      __syncthreads();
      // ---- phase B: z_next += 0.5*(t@W2), split-K 2-way across wgs via atomics
      if (tid < 128) {
        const float4* wc4 = ldsB + ciA*129;
        const float*  tr  = tstage + rA*512;
        float a0=0,a1=0,a2=0,a3=0;
        #pragma unroll 8
        for (int j=0;j<128;j++){
          float4 wv = wc4[j];
          float4 tv = *(const float4*)(tr + 4*j);
          a0 += tv.x*wv.x; a1 += tv.y*wv.y; a2 += tv.z*wv.z; a3 += tv.w*wv.w;
        }
        atomicAdd(&zn[bA*512 + c2B], 0.5f*((a0+a1)+(a2+a3)));
      }
      if (i==7 && tid>=128) {  // init liquid pre-act buffers with biases for L1
        int idx = w*128 + (tid-128);
        if (idx < 2048){ int r=idx>>9, c=idx&511; G[(g*4+r)*512+c] = l_b[c]; }
        else { int i2=idx-2048; int r=i2>>9, c=i2&511; TA[(g*4+r)*512+c] = l_bt[c]; }
      }
      gbar(flags, w, epoch);
    }
    // ---- L1: liquid gate/tau pre-activations, split-K via atomics (v8 verbatim) ----
    {
      int sub = tid>>7, l = tid&127;
      int r = l>>5, b = g*4+r;
      int c2 = (w&15)*32 + (l&31);
      int kh = w>>4;
      const float* inrow = (kh==0) ? (Z + b*512) : (H + b*512);
      const float* Wc = (sub ? (kh==0 ? wsF+OF_LWTIT : wsF+OF_LWTHT)
                             : (kh==0 ? wsF+OF_LWIT  : wsF+OF_LWHT)) + (size_t)c2*512;
      float a0=0,a1=0,a2=0,a3=0;
      #pragma unroll 4
      for (int k=0;k<512;k+=4){
        float4 iv = *(const float4*)(inrow + k);
        float4 wv = *(const float4*)(Wc + k);
        a0 += iv.x*wv.x; a1 += iv.y*wv.y; a2 += iv.z*wv.z; a3 += iv.w*wv.w;
      }
      atomicAdd(sub ? &TA[b*512+c2] : &G[b*512+c2], (a0+a1)+(a2+a3));
    }
    gbar(flags, w, epoch);
    // ---- L2: h update (+snapshots at write step) | c_pre for next step (v8 verbatim) ----
    if (w < 16) {
      if (tid < 128) {
        int r = tid>>5, b = g*4+r;
        int c2 = w*32 + (tid&31);
        float gv = tanhf(G[b*512+c2]);
        float tv = softplusf_(TA[b*512+c2]) + 1.0f;
        float hv = H[b*512+c2];
        float hn = hv + (gv - hv)/tv;
        H[b*512+c2] = hn;
        if (write_pos[b] == s) { ZS[b*512+c2] = Z[b*512+c2]; HS[b*512+c2] = hn; }
      }
    } else if (s+1 < 32) {
      int r = tid>>6, b = g*4+r;
      int c = (w-16)*64 + (tid&63);
      int tok = tokens[b*64 + s+1];
      const float* xr = embed_W + (size_t)tok*256;
      const float* wc = wsF + OF_W1XT + (size_t)c*256;
      float a0=0,a1=0,a2=0,a3=0;
      #pragma unroll 4
      for (int k=0;k<256;k+=4){
        float4 xv = *(const float4*)(xr + k);
        float4 wv = *(const float4*)(wc + k);
        a0 += xv.x*wv.x; a1 += xv.y*wv.y; a2 += xv.z*wv.z; a3 += xv.w*wv.w;
      }
      CP[b*1024 + c] = u_b1[c] + ((a0+a1)+(a2+a3));
    }
    gbar(flags, w, epoch);
  }
}

// ---------------- kernel 3: v_pred + decay-weighted scatter into M (v8 verbatim) ----------------
__global__ void __launch_bounds__(256) emma_k3(const float* z2v_W, const float* z2v_b,
                                               int* wsI, float* wsF)
{
  const int b = blockIdx.x, c = threadIdx.x;
  const float* zs = wsF + OF_ZS + b*512;
  const float* hs = wsF + OF_HS + b*512;
  float acc = z2v_b[c];
  for (int k=0;k<512;k++) acc += zs[k]*z2v_W[k*256 + c];
  for (int k=0;k<512;k++) acc += hs[k]*z2v_W[(512+k)*256 + c];
  __shared__ float red[256];
  red[c]=acc*acc; __syncthreads();
  for (int st=128; st; st>>=1){ if (c<st) red[c]+=red[c+st]; __syncthreads(); }
  float inv = 1.f/fmaxf(sqrtf(red[0]),1e-12f);
  float vp = acc*inv;
  float f = wsF[OF_DFAC + b];
  for (int j=0;j<16;j++){
    int slot = wsI[2048 + b*16 + j];
    float wj = wsF[OF_TOPW + b*16 + j];
    atomicAdd(&wsF[OF_M + (size_t)slot*256 + c], f*wj*vp);
  }
}

// ---------------- kernel 4: v_mem read, normalize, logits (v8 verbatim) ----------------
__global__ void __launch_bounds__(256) emma_k4(const float* value_W, int* wsI, float* wsF,
                                               float* out)
{
  const int b = blockIdx.x, c = threadIdx.x;
  float m = 0.f;
  for (int j=0;j<16;j++){
    int slot = wsI[2048 + b*16 + j];
    m += wsF[OF_TOPW + b*16 + j] * wsF[OF_M + (size_t)slot*256 + c];
  }
  __shared__ float red[256];
  __shared__ float vn[256];
  red[c]=m*m; __syncthreads();
  for (int st=128; st; st>>=1){ if (c<st) red[c]+=red[c+st]; __syncthreads(); }
  float inv = 1.f/fmaxf(sqrtf(red[0]),1e-12f);
  vn[c] = m*inv;
  __syncthreads();
  float scale = wsF[OF_SCALE];
  for (int q=0;q<4;q++){
    int val = q*256 + c;
    const float* row = value_W + (size_t)val*256;
    float d0=0,d1=0,d2=0,d3=0;
    #pragma unroll 4
    for (int k=0;k<256;k+=4){
      float4 rv = *(const float4*)(row + k);
      d0 += vn[k+0]*rv.x; d1 += vn[k+1]*rv.y; d2 += vn[k+2]*rv.z; d3 += vn[k+3]*rv.w;
    }
    out[b*1024 + val] = scale * wsF[OF_RNV + val] * ((d0+d1)+(d2+d3));
  }
}

extern "C" void kernel_launch(void* const* d_in, const int* in_sizes, int n_in,
                              void* d_out, int out_size, void* d_ws, size_t ws_size,
                              hipStream_t stream)
{
  const int*   tokens    = (const int*)  d_in[0];
  const int*   key_ids   = (const int*)  d_in[1];
  const int*   write_pos = (const int*)  d_in[2];
  const float* embed_W   = (const float*)d_in[5];
  const float* key_W     = (const float*)d_in[6];
  const float* value_W   = (const float*)d_in[7];
  const float* u_W1      = (const float*)d_in[8];
  const float* u_b1      = (const float*)d_in[9];
  const float* u_W2      = (const float*)d_in[10];
  const float* u_b2      = (const float*)d_in[11];
  const float* l_Wi      = (const float*)d_in[12];
  const float* l_Wh      = (const float*)d_in[13];
  const float* l_b       = (const float*)d_in[14];
  const float* l_Wti     = (const float*)d_in[15];
  const float* l_Wth     = (const float*)d_in[16];
  const float* l_bt      = (const float*)d_in[17];
  const float* h0        = (const float*)d_in[18];
  const float* z2v_W     = (const float*)d_in[19];
  const float* z2v_b     = (const float*)d_in[20];
  const float* lsr       = (const float*)d_in[21];
  const float* slot_keys = (const float*)d_in[22];

  int*   wsI = (int*)d_ws;
  float* wsF = (float*)((char*)d_ws + 16384);
  float* out = (float*)d_out;

  hipLaunchKernelGGL(emma_k1a, dim3(325), dim3(256), 0, stream,
                     key_ids, write_pos, key_W, value_W, slot_keys, lsr, wsI, wsF);
  hipLaunchKernelGGL(emma_k1b, dim3(32), dim3(256), 0, stream, wsI, wsF);
  // weight transposes (row-major [R][1<<shift] -> col-major):
  hipLaunchKernelGGL(emma_tr, dim3(512), dim3(256), 0, stream, u_W1,            wsF+OF_W1ZT, 10, 512*1024);
  hipLaunchKernelGGL(emma_tr, dim3(512), dim3(256), 0, stream, u_W1 + 512*1024, wsF+OF_W1XT, 10, 256*1024);
  hipLaunchKernelGGL(emma_tr, dim3(512), dim3(256), 0, stream, u_W2,            wsF+OF_W2T,   9, 1024*512);
  hipLaunchKernelGGL(emma_tr, dim3(512), dim3(256), 0, stream, l_Wi,            wsF+OF_LWIT,  9, 512*512);
  hipLaunchKernelGGL(emma_tr, dim3(512), dim3(256), 0, stream, l_Wh,            wsF+OF_LWHT,  9, 512*512);
  hipLaunchKernelGGL(emma_tr, dim3(512), dim3(256), 0, stream, l_Wti,           wsF+OF_LWTIT, 9, 512*512);
  hipLaunchKernelGGL(emma_tr, dim3(512), dim3(256), 0, stream, l_Wth,           wsF+OF_LWTHT, 9, 512*512);
  {
    void* args[] = { (void*)&tokens, (void*)&write_pos, (void*)&embed_W,
                     (void*)&u_b1, (void*)&u_b2, (void*)&l_b, (void*)&l_bt, (void*)&h0,
                     (void*)&wsI, (void*)&wsF };
    hipLaunchCooperativeKernel(reinterpret_cast<void*>(emma_k2), dim3(256), dim3(256),
                               args, 0, stream);
  }
  hipLaunchKernelGGL(emma_k3, dim3(32), dim3(256), 0, stream, z2v_W, z2v_b, wsI, wsF);
  hipLaunchKernelGGL(emma_k4, dim3(32), dim3(256), 0, stream, value_W, wsI, wsF, out);
}

// Round 2
// 4657.159 us; speedup vs baseline: 2.3496x; 1.2499x over previous
//
#include <hip/hip_runtime.h>
#include <math.h>

// EMMA_38792144617759 v10 — v9 (passed, 5.82ms) with ONE change class: the 512
// DEQ-internal global barriers become FENCE-FREE (no buffer_wbl2/buffer_inv).
// All data crossing WGs inside the DEQ loop (z staging, T, zn pre-bias, G/TA
// bias init) moves via agent-scope relaxed atomics (sc1, LLC-coherent, same
// point where the existing atomicAdds already operate). Heavy fenced gbar kept
// at step granularity (preamble, post-L1, post-L2) so all normal cached
// accesses in L1/L2 phases keep v9 semantics. Rationale: rocprof shows
// VALUBusy 7%, HBM 1.9% — each 9.4us phase is ~7us of barrier cache
// maintenance (wbl2+inv on 256 WGs) that the sc1 data path makes unnecessary.

#define NGRP 8
#define WPG  32

// ---- workspace float offsets (wsF = d_ws + 16KB; first 16KB is int region) ----
#define OF_SCALE  0
#define OF_DFAC   32
#define OF_RNV    64
#define OF_TOPW   1088
#define OF_SCORES 1600      // 32*4096
#define OF_Z      132672    // 2*32*512 (double-buffered z)
#define OF_T      165440    // 32*1024
#define OF_CP     198208    // 32*1024
#define OF_G      230976    // 32*512
#define OF_TAU    247360    // 32*512
#define OF_H      263744    // 32*512
#define OF_ZS     280128    // 32*512
#define OF_HS     296512    // 32*512
#define OF_M      312896    // 4096*256
// transposed weight copies (filled by emma_tr before k2):
#define OF_W1ZT   1361472   // [1024 c][512 k]  = u_W1[k][c], k<512
#define OF_W1XT   1885760   // [1024 c][256 k]  = u_W1[512+k][c]
#define OF_W2T    2147904   // [512 c][1024 k]  = u_W2[k][c]
#define OF_LWIT   2672192   // [512 c][512 k]   = l_Wi[k][c]
#define OF_LWHT   2934336   // [512 c][512 k]   = l_Wh[k][c]
#define OF_LWTIT  3196480   // [512 c][512 k]   = l_Wti[k][c]
#define OF_LWTHT  3458624   // [512 c][512 k]   = l_Wth[k][c]
// end: 3720768 floats (~14.2MB) + 16KB ints
// wsI: [0..2048) barrier flags region (g*32+w used), [2048..2560) top_i

__device__ __forceinline__ float softplusf_(float x){ return x > 20.f ? x : log1pf(expf(x)); }

__device__ __forceinline__ float cldf(const float* p){
  return __hip_atomic_load(p, __ATOMIC_RELAXED, __HIP_MEMORY_SCOPE_AGENT);
}
__device__ __forceinline__ void cstf(float* p, float v){
  __hip_atomic_store(p, v, __ATOMIC_RELAXED, __HIP_MEMORY_SCOPE_AGENT);
}

// Heavy fence barrier (PROVEN in R4) — used at step granularity only.
__device__ __forceinline__ void gbar(int* flags, int w, int& epoch){
  __syncthreads();
  epoch++;
  if (threadIdx.x == 0){
    __builtin_amdgcn_fence(__ATOMIC_RELEASE, "agent");
    __hip_atomic_store(&flags[w], epoch, __ATOMIC_RELAXED, __HIP_MEMORY_SCOPE_AGENT);
  }
  if (threadIdx.x < 32){
    while (__hip_atomic_load(&flags[threadIdx.x], __ATOMIC_RELAXED,
                             __HIP_MEMORY_SCOPE_AGENT) < epoch)
      __builtin_amdgcn_s_sleep(1);
    __builtin_amdgcn_fence(__ATOMIC_ACQUIRE, "agent");
  }
  __syncthreads();
}

// Light fence-free barrier: all DEQ-internal cross-WG data goes through sc1
// (LLC) ops, so no L2 writeback/invalidate is needed — only store-drain +
// flag handshake. vmcnt(0) before s_barrier ensures every wave's sc1 stores
// (and atomics) have reached the coherence point before the flag is raised.
__device__ __forceinline__ void lbar(int* flags, int w, int& epoch){
  asm volatile("s_waitcnt vmcnt(0)" ::: "memory");
  __syncthreads();
  epoch++;
  if (threadIdx.x == 0)
    __hip_atomic_store(&flags[w], epoch, __ATOMIC_RELAXED, __HIP_MEMORY_SCOPE_AGENT);
  if (threadIdx.x < 32){
    while (__hip_atomic_load(&flags[threadIdx.x], __ATOMIC_RELAXED,
                             __HIP_MEMORY_SCOPE_AGENT) < epoch)
      __builtin_amdgcn_s_sleep(1);
  }
  asm volatile("" ::: "memory");
  __syncthreads();
}

// ---------------- kernel 0: generic row-major -> col-major transpose ----------------
__global__ void __launch_bounds__(256) emma_tr(const float* src, float* dst,
                                               int shift, int total)
{
  const int R = total >> shift;
  const int cmask = (1 << shift) - 1;
  for (int idx = blockIdx.x*256 + threadIdx.x; idx < total; idx += gridDim.x*256){
    int r = idx >> shift, c = idx & cmask;
    dst[(size_t)c * R + r] = src[idx];
  }
}

// ---------------- kernel 1a: scores, M zero, value-row norms, misc (v9 verbatim) ----------------
__global__ void __launch_bounds__(256) emma_k1a(
    const int* key_ids, const int* write_pos,
    const float* key_W, const float* value_W, const float* slot_keys,
    const float* lsr, int* wsI, float* wsF)
{
  const int wg = blockIdx.x, tid = threadIdx.x;
  if (wg < 256) {
    const int b = wg >> 3, chunk = wg & 7;
    __shared__ __align__(16) float s_kv[256];
    __shared__ float red[256];
    float v = key_W[key_ids[b]*256 + tid];
    red[tid] = v*v; __syncthreads();
    for (int st=128; st; st>>=1){ if (tid<st) red[tid]+=red[tid+st]; __syncthreads(); }
    float inv = 1.f/fmaxf(sqrtf(red[0]), 1e-12f);
    s_kv[tid] = v*inv;
    __syncthreads();
    const int lane = tid & 63, wv = tid >> 6;
    float4 kv4 = *(const float4*)(s_kv + lane*4);
    for (int slot = chunk*512 + wv; slot < chunk*512 + 512; slot += 4){
      float4 sk = *(const float4*)(slot_keys + (size_t)slot*256 + lane*4);
      float p = kv4.x*sk.x + kv4.y*sk.y + kv4.z*sk.z + kv4.w*sk.w;
      #pragma unroll
      for (int m=32;m;m>>=1) p += __shfl_xor(p, m, 64);
      if (lane==0) wsF[OF_SCORES + b*4096 + slot] = p;
    }
  } else if (wg < 320) {
    const int j = wg - 256;
    for (int i=tid;i<16384;i+=256) wsF[OF_M + j*16384 + i] = 0.f;
  } else if (wg < 324) {
    const int row = (wg-320)*256 + tid;
    float ss=0.f; const float* r = value_W + (size_t)row*256;
    for (int k=0;k<256;k++){ float x=r[k]; ss += x*x; }
    wsF[OF_RNV + row] = 1.f/fmaxf(sqrtf(ss), 1e-12f);
  } else {
    for (int i=tid;i<2048;i+=256) wsI[i]=0;
    __shared__ int pres[32];
    if (tid<32){ int p=0; for (int bb=0;bb<32;bb++) if (write_pos[bb]==tid) p=1; pres[tid]=p; }
    __syncthreads();
    if (tid<32){
      int wp = write_pos[tid]; float f=1.f;
      for (int s=wp+1;s<32;s++) if (pres[s]) f *= 0.997f;
      wsF[OF_DFAC + tid] = f;
    }
    if (tid==0) wsF[OF_SCALE] = softplusf_(lsr[0]) + 1e-3f;
  }
}

// ---------------- kernel 1b: exact top-16 + softmax (v9 verbatim) ----------------
__global__ void __launch_bounds__(256) emma_k1b(int* wsI, float* wsF)
{
  const int b = blockIdx.x, tid = threadIdx.x;
  __shared__ float s_sc[4096];
  __shared__ float s_rv[256]; __shared__ int s_ri[256];
  __shared__ float s_tv[16];
  for (int n=tid;n<4096;n+=256) s_sc[n] = wsF[OF_SCORES + b*4096 + n];
  __syncthreads();
  for (int j=0;j<16;j++){
    float bv = -3.0e38f; int bi = 0x7fffffff;
    for (int n=tid;n<4096;n+=256){
      float v = s_sc[n];
      if (v > bv || (v == bv && n < bi)) { bv=v; bi=n; }
    }
    s_rv[tid]=bv; s_ri[tid]=bi; __syncthreads();
    for (int st=128; st; st>>=1){
      if (tid<st){
        float v2=s_rv[tid+st]; int i2=s_ri[tid+st];
        if (v2 > s_rv[tid] || (v2==s_rv[tid] && i2 < s_ri[tid])) { s_rv[tid]=v2; s_ri[tid]=i2; }
      }
      __syncthreads();
    }
    if (tid==0){
      s_tv[j] = s_rv[0];
      wsI[2048 + b*16 + j] = s_ri[0];
      s_sc[s_ri[0]] = -3.0e38f;
    }
    __syncthreads();
  }
  if (tid==0){
    float mx = s_tv[0], sum=0.f, w[16];
    for (int j=0;j<16;j++){ w[j]=expf(s_tv[j]-mx); sum+=w[j]; }
    for (int j=0;j<16;j++) wsF[OF_TOPW + b*16 + j] = w[j]/sum;
  }
}

// ---------------- kernel 2: persistent trajectory (v9 structure; fence-free DEQ barriers) ----------------
__global__ void __launch_bounds__(256, 1) emma_k2(
    const int* tokens, const int* write_pos,
    const float* embed_W, const float* u_b1, const float* u_b2,
    const float* l_b, const float* l_bt, const float* h0,
    int* wsI, float* wsF)
{
  const int g = blockIdx.x & 7;
  const int w = blockIdx.x >> 3;
  const int tid = threadIdx.x;
  int* flags = wsI + g*32;
  int epoch = 0;

  float* Z  = wsF + OF_Z;
  float* T  = wsF + OF_T;
  float* CP = wsF + OF_CP;
  float* G  = wsF + OF_G;
  float* TA = wsF + OF_TAU;
  float* H  = wsF + OF_H;
  float* ZS = wsF + OF_ZS;
  float* HS = wsF + OF_HS;

  __shared__ __align__(16) float4 ldsA[32*129];   // W1ZT cols [w*32, w*32+32)
  __shared__ __align__(16) float4 ldsB[32*129];   // W2T cols [(w&15)*32,+32), k-half (w>>4)
  __shared__ __align__(16) float zstage[2048];    // this group's z [4][512]
  __shared__ __align__(16) float tstage[2048];    // this group's t-half [4][512]

  // ---- stage per-WG DEQ weight slices into LDS (once) ----
  {
    const float* gA = wsF + OF_W1ZT + (size_t)(w*32)*512;
    const float* gB = wsF + OF_W2T  + (size_t)((w&15)*32)*1024 + (size_t)(w>>4)*512;
    for (int idx4 = tid; idx4 < 4096; idx4 += 256){
      int ci = idx4 >> 7, j = idx4 & 127;
      ldsA[ci*129 + j] = *(const float4*)(gA + (size_t)ci*512  + 4*j);
      ldsB[ci*129 + j] = *(const float4*)(gB + (size_t)ci*1024 + 4*j);
    }
  }

  // per-thread loop-invariant constants
  const int rA  = tid >> 5;            // valid for tid<128 phases
  const int bA  = g*4 + (rA & 3);
  const int ciA = tid & 31;
  const int cA  = w*32 + ciA;          // phase A output col
  const int c2B = (w&15)*32 + ciA;     // phase B output col
  const int kh  = w >> 4;              // phase B k-half
  float b2half = 0.f; int znr = 0, znc = 0;
  if (tid < 64){ int idx = w*64 + tid; znr = idx>>9; znc = idx&511; b2half = 0.5f*u_b2[znc]; }

  // ---- preamble: z=0, h=h0 | c_pre for step 0 (v9 verbatim) ----
  if (w < 16) {
    int idx = w*256 + tid;
    if (idx < 2048) { int r=idx>>9, c=idx&511; Z[(g*4+r)*512 + c] = 0.f; }
    else { int i2=idx-2048; int r=i2>>9, c=i2&511; H[(g*4+r)*512 + c] = h0[c]; }
  } else {
    int r = tid>>6, b = g*4+r;
    int c = (w-16)*64 + (tid&63);
    int tok = tokens[b*64 + 0];
    const float* xr = embed_W + (size_t)tok*256;
    const float* wc = wsF + OF_W1XT + (size_t)c*256;
    float a0=0,a1=0,a2=0,a3=0;
    #pragma unroll 4
    for (int k=0;k<256;k+=4){
      float4 xv = *(const float4*)(xr + k);
      float4 wv = *(const float4*)(wc + k);
      a0 += xv.x*wv.x; a1 += xv.y*wv.y; a2 += xv.z*wv.z; a3 += xv.w*wv.w;
    }
    CP[b*1024 + c] = u_b1[c] + ((a0+a1)+(a2+a3));
  }
  gbar(flags, w, epoch);

  for (int s=0;s<32;s++){
    // CP fixed across the 8 DEQ iters — hoist (normal load; heavy gbar precedes).
    float cpv = (tid < 128) ? CP[bA*1024 + cA] : 0.f;
    for (int i=0;i<8;i++){
      float* zc = Z + (i&1)*16384;
      float* zn = Z + ((i&1)^1)*16384;
      // stage this group's z global(LLC)->LDS, coherent scalar loads
      #pragma unroll
      for (int k=0;k<8;k++){
        int idx = k*256 + tid;
        zstage[idx] = cldf(&zc[g*2048 + idx]);
      }
      __syncthreads();
      // ---- phase A: t = tanh(z@W1z + c_pre); also pre-bias z_next
      if (tid < 128) {
        const float4* wc4 = ldsA + ciA*129;
        const float*  zr  = zstage + rA*512;
        float a0=0,a1=0,a2=0,a3=0;
        #pragma unroll 8
        for (int j=0;j<128;j++){
          float4 wv = wc4[j];
          float4 zv = *(const float4*)(zr + 4*j);
          a0 += zv.x*wv.x; a1 += zv.y*wv.y; a2 += zv.z*wv.z; a3 += zv.w*wv.w;
        }
        cstf(&T[bA*1024 + cA], tanhf(cpv + (a0+a1)+(a2+a3)));
      }
      if (tid < 64) {
        cstf(&zn[(g*4+znr)*512 + znc], zstage[znr*512 + znc] + b2half);
      }
      lbar(flags, w, epoch);
      // stage this group's t k-half global(LLC)->LDS, coherent scalar loads
      #pragma unroll
      for (int k=0;k<8;k++){
        int idx = k*256 + tid;
        int r = idx>>9, c = idx&511;
        tstage[r*512 + c] = cldf(&T[(size_t)(g*4+r)*1024 + kh*512 + c]);
      }
      __syncthreads();
      // ---- phase B: z_next += 0.5*(t@W2), split-K 2-way across wgs via atomics
      if (tid < 128) {
        const float4* wc4 = ldsB + ciA*129;
        const float*  tr  = tstage + rA*512;
        float a0=0,a1=0,a2=0,a3=0;
        #pragma unroll 8
        for (int j=0;j<128;j++){
          float4 wv = wc4[j];
          float4 tv = *(const float4*)(tr + 4*j);
          a0 += tv.x*wv.x; a1 += tv.y*wv.y; a2 += tv.z*wv.z; a3 += tv.w*wv.w;
        }
        atomicAdd(&zn[bA*512 + c2B], 0.5f*((a0+a1)+(a2+a3)));
      }
      if (i==7 && tid>=128) {  // init liquid pre-act buffers with biases (sc1 -> LLC)
        int idx = w*128 + (tid-128);
        if (idx < 2048){ int r=idx>>9, c=idx&511; cstf(&G[(g*4+r)*512+c], l_b[c]); }
        else { int i2=idx-2048; int r=i2>>9, c=i2&511; cstf(&TA[(g*4+r)*512+c], l_bt[c]); }
      }
      lbar(flags, w, epoch);
    }
    // ---- L1: liquid gate/tau pre-activations, split-K via atomics (v9 verbatim) ----
    {
      int sub = tid>>7, l = tid&127;
      int r = l>>5, b = g*4+r;
      int c2 = (w&15)*32 + (l&31);
      const float* inrow = (kh==0) ? (Z + b*512) : (H + b*512);
      const float* Wc = (sub ? (kh==0 ? wsF+OF_LWTIT : wsF+OF_LWTHT)
                             : (kh==0 ? wsF+OF_LWIT  : wsF+OF_LWHT)) + (size_t)c2*512;
      float a0=0,a1=0,a2=0,a3=0;
      #pragma unroll 4
      for (int k=0;k<512;k+=4){
        float4 iv = *(const float4*)(inrow + k);
        float4 wv = *(const float4*)(Wc + k);
        a0 += iv.x*wv.x; a1 += iv.y*wv.y; a2 += iv.z*wv.z; a3 += iv.w*wv.w;
      }
      atomicAdd(sub ? &TA[b*512+c2] : &G[b*512+c2], (a0+a1)+(a2+a3));
    }
    gbar(flags, w, epoch);
    // ---- L2: h update (+snapshots at write step) | c_pre for next step (v9 verbatim) ----
    if (w < 16) {
      if (tid < 128) {
        int r = tid>>5, b = g*4+r;
        int c2 = w*32 + (tid&31);
        float gv = tanhf(G[b*512+c2]);
        float tv = softplusf_(TA[b*512+c2]) + 1.0f;
        float hv = H[b*512+c2];
        float hn = hv + (gv - hv)/tv;
        H[b*512+c2] = hn;
        if (write_pos[b] == s) { ZS[b*512+c2] = Z[b*512+c2]; HS[b*512+c2] = hn; }
      }
    } else if (s+1 < 32) {
      int r = tid>>6, b = g*4+r;
      int c = (w-16)*64 + (tid&63);
      int tok = tokens[b*64 + s+1];
      const float* xr = embed_W + (size_t)tok*256;
      const float* wc = wsF + OF_W1XT + (size_t)c*256;
      float a0=0,a1=0,a2=0,a3=0;
      #pragma unroll 4
      for (int k=0;k<256;k+=4){
        float4 xv = *(const float4*)(xr + k);
        float4 wv = *(const float4*)(wc + k);
        a0 += xv.x*wv.x; a1 += xv.y*wv.y; a2 += xv.z*wv.z; a3 += xv.w*wv.w;
      }
      CP[b*1024 + c] = u_b1[c] + ((a0+a1)+(a2+a3));
    }
    gbar(flags, w, epoch);
  }
}

// ---------------- kernel 3: v_pred + decay-weighted scatter into M (v9 verbatim) ----------------
__global__ void __launch_bounds__(256) emma_k3(const float* z2v_W, const float* z2v_b,
                                               int* wsI, float* wsF)
{
  const int b = blockIdx.x, c = threadIdx.x;
  const float* zs = wsF + OF_ZS + b*512;
  const float* hs = wsF + OF_HS + b*512;
  float acc = z2v_b[c];
  for (int k=0;k<512;k++) acc += zs[k]*z2v_W[k*256 + c];
  for (int k=0;k<512;k++) acc += hs[k]*z2v_W[(512+k)*256 + c];
  __shared__ float red[256];
  red[c]=acc*acc; __syncthreads();
  for (int st=128; st; st>>=1){ if (c<st) red[c]+=red[c+st]; __syncthreads(); }
  float inv = 1.f/fmaxf(sqrtf(red[0]),1e-12f);
  float vp = acc*inv;
  float f = wsF[OF_DFAC + b];
  for (int j=0;j<16;j++){
    int slot = wsI[2048 + b*16 + j];
    float wj = wsF[OF_TOPW + b*16 + j];
    atomicAdd(&wsF[OF_M + (size_t)slot*256 + c], f*wj*vp);
  }
}

// ---------------- kernel 4: v_mem read, normalize, logits (v9 verbatim) ----------------
__global__ void __launch_bounds__(256) emma_k4(const float* value_W, int* wsI, float* wsF,
                                               float* out)
{
  const int b = blockIdx.x, c = threadIdx.x;
  float m = 0.f;
  for (int j=0;j<16;j++){
    int slot = wsI[2048 + b*16 + j];
    m += wsF[OF_TOPW + b*16 + j] * wsF[OF_M + (size_t)slot*256 + c];
  }
  __shared__ float red[256];
  __shared__ float vn[256];
  red[c]=m*m; __syncthreads();
  for (int st=128; st; st>>=1){ if (c<st) red[c]+=red[c+st]; __syncthreads(); }
  float inv = 1.f/fmaxf(sqrtf(red[0]),1e-12f);
  vn[c] = m*inv;
  __syncthreads();
  float scale = wsF[OF_SCALE];
  for (int q=0;q<4;q++){
    int val = q*256 + c;
    const float* row = value_W + (size_t)val*256;
    float d0=0,d1=0,d2=0,d3=0;
    #pragma unroll 4
    for (int k=0;k<256;k+=4){
      float4 rv = *(const float4*)(row + k);
      d0 += vn[k+0]*rv.x; d1 += vn[k+1]*rv.y; d2 += vn[k+2]*rv.z; d3 += vn[k+3]*rv.w;
    }
    out[b*1024 + val] = scale * wsF[OF_RNV + val] * ((d0+d1)+(d2+d3));
  }
}

extern "C" void kernel_launch(void* const* d_in, const int* in_sizes, int n_in,
                              void* d_out, int out_size, void* d_ws, size_t ws_size,
                              hipStream_t stream)
{
  const int*   tokens    = (const int*)  d_in[0];
  const int*   key_ids   = (const int*)  d_in[1];
  const int*   write_pos = (const int*)  d_in[2];
  const float* embed_W   = (const float*)d_in[5];
  const float* key_W     = (const float*)d_in[6];
  const float* value_W   = (const float*)d_in[7];
  const float* u_W1      = (const float*)d_in[8];
  const float* u_b1      = (const float*)d_in[9];
  const float* u_W2      = (const float*)d_in[10];
  const float* u_b2      = (const float*)d_in[11];
  const float* l_Wi      = (const float*)d_in[12];
  const float* l_Wh      = (const float*)d_in[13];
  const float* l_b       = (const float*)d_in[14];
  const float* l_Wti     = (const float*)d_in[15];
  const float* l_Wth     = (const float*)d_in[16];
  const float* l_bt      = (const float*)d_in[17];
  const float* h0        = (const float*)d_in[18];
  const float* z2v_W     = (const float*)d_in[19];
  const float* z2v_b     = (const float*)d_in[20];
  const float* lsr       = (const float*)d_in[21];
  const float* slot_keys = (const float*)d_in[22];

  int*   wsI = (int*)d_ws;
  float* wsF = (float*)((char*)d_ws + 16384);
  float* out = (float*)d_out;

  hipLaunchKernelGGL(emma_k1a, dim3(325), dim3(256), 0, stream,
                     key_ids, write_pos, key_W, value_W, slot_keys, lsr, wsI, wsF);
  hipLaunchKernelGGL(emma_k1b, dim3(32), dim3(256), 0, stream, wsI, wsF);
  // weight transposes (row-major [R][1<<shift] -> col-major):
  hipLaunchKernelGGL(emma_tr, dim3(512), dim3(256), 0, stream, u_W1,            wsF+OF_W1ZT, 10, 512*1024);
  hipLaunchKernelGGL(emma_tr, dim3(512), dim3(256), 0, stream, u_W1 + 512*1024, wsF+OF_W1XT, 10, 256*1024);
  hipLaunchKernelGGL(emma_tr, dim3(512), dim3(256), 0, stream, u_W2,            wsF+OF_W2T,   9, 1024*512);
  hipLaunchKernelGGL(emma_tr, dim3(512), dim3(256), 0, stream, l_Wi,            wsF+OF_LWIT,  9, 512*512);
  hipLaunchKernelGGL(emma_tr, dim3(512), dim3(256), 0, stream, l_Wh,            wsF+OF_LWHT,  9, 512*512);
  hipLaunchKernelGGL(emma_tr, dim3(512), dim3(256), 0, stream, l_Wti,           wsF+OF_LWTIT, 9, 512*512);
  hipLaunchKernelGGL(emma_tr, dim3(512), dim3(256), 0, stream, l_Wth,           wsF+OF_LWTHT, 9, 512*512);
  {
    void* args[] = { (void*)&tokens, (void*)&write_pos, (void*)&embed_W,
                     (void*)&u_b1, (void*)&u_b2, (void*)&l_b, (void*)&l_bt, (void*)&h0,
                     (void*)&wsI, (void*)&wsF };
    hipLaunchCooperativeKernel(reinterpret_cast<void*>(emma_k2), dim3(256), dim3(256),
                               args, 0, stream);
  }
  hipLaunchKernelGGL(emma_k3, dim3(32), dim3(256), 0, stream, z2v_W, z2v_b, wsI, wsF);
  hipLaunchKernelGGL(emma_k4, dim3(32), dim3(256), 0, stream, value_W, wsI, wsF, out);
}

// Round 3
// 4354.357 us; speedup vs baseline: 2.5130x; 1.0695x over previous
//
#include <hip/hip_runtime.h>
#include <math.h>

// EMMA_38792144617759 v11 — v10 (passed, 4.66ms) with ONE change class: the
// remaining 64 HEAVY barriers (post-L1/post-L2 gbar, preamble) become the
// fence-free lbar too. Enabler: ALL shared mutable buffers (Z,T,CP,G,TA,H,
// ZS,HS) now move exclusively via sc1 agent-relaxed atomics (the path v10
// proved), with the L1-phase input rows (Z or H) LDS-staged like the DEQ
// stagings. No normal cached access ever touches cross-WG mutable data, so
// no buffer_wbl2/buffer_inv is needed anywhere -> read-only weights (liquid,
// W1XT, embed) stay L1/L2-resident across all 32 steps. rocprof v10: 64 heavy
// phases ~40us each (~2.6ms of k2's 4.29ms), FETCH 703MB = per-step weight
// re-streaming after invalidates. Also: zstage/tstage row stride padded to
// 520 floats (rows land on banks 0/8/16/24) -> activation ds_read_b128
// conflict-free in phases A/B/L1.

#define NGRP 8
#define WPG  32

// ---- workspace float offsets (wsF = d_ws + 16KB; first 16KB is int region) ----
#define OF_SCALE  0
#define OF_DFAC   32
#define OF_RNV    64
#define OF_TOPW   1088
#define OF_SCORES 1600      // 32*4096
#define OF_Z      132672    // 2*32*512 (double-buffered z)
#define OF_T      165440    // 32*1024
#define OF_CP     198208    // 32*1024
#define OF_G      230976    // 32*512
#define OF_TAU    247360    // 32*512
#define OF_H      263744    // 32*512
#define OF_ZS     280128    // 32*512
#define OF_HS     296512    // 32*512
#define OF_M      312896    // 4096*256
// transposed weight copies (filled by emma_tr before k2):
#define OF_W1ZT   1361472   // [1024 c][512 k]  = u_W1[k][c], k<512
#define OF_W1XT   1885760   // [1024 c][256 k]  = u_W1[512+k][c]
#define OF_W2T    2147904   // [512 c][1024 k]  = u_W2[k][c]
#define OF_LWIT   2672192   // [512 c][512 k]   = l_Wi[k][c]
#define OF_LWHT   2934336   // [512 c][512 k]   = l_Wh[k][c]
#define OF_LWTIT  3196480   // [512 c][512 k]   = l_Wti[k][c]
#define OF_LWTHT  3458624   // [512 c][512 k]   = l_Wth[k][c]
// end: 3720768 floats (~14.2MB) + 16KB ints
// wsI: [0..2048) barrier flags region (g*32+w used), [2048..2560) top_i

__device__ __forceinline__ float softplusf_(float x){ return x > 20.f ? x : log1pf(expf(x)); }

__device__ __forceinline__ float cldf(const float* p){
  return __hip_atomic_load(p, __ATOMIC_RELAXED, __HIP_MEMORY_SCOPE_AGENT);
}
__device__ __forceinline__ void cstf(float* p, float v){
  __hip_atomic_store(p, v, __ATOMIC_RELAXED, __HIP_MEMORY_SCOPE_AGENT);
}

// Light fence-free barrier (PROVEN in v10): all cross-WG data goes through sc1
// (LLC) ops, so no L2 writeback/invalidate is needed — only store-drain +
// flag handshake. vmcnt(0) before s_barrier ensures every wave's sc1 stores
// (and atomics) have reached the coherence point before the flag is raised.
__device__ __forceinline__ void lbar(int* flags, int w, int& epoch){
  asm volatile("s_waitcnt vmcnt(0)" ::: "memory");
  __syncthreads();
  epoch++;
  if (threadIdx.x == 0)
    __hip_atomic_store(&flags[w], epoch, __ATOMIC_RELAXED, __HIP_MEMORY_SCOPE_AGENT);
  if (threadIdx.x < 32){
    while (__hip_atomic_load(&flags[threadIdx.x], __ATOMIC_RELAXED,
                             __HIP_MEMORY_SCOPE_AGENT) < epoch)
      __builtin_amdgcn_s_sleep(1);
  }
  asm volatile("" ::: "memory");
  __syncthreads();
}

// ---------------- kernel 0: generic row-major -> col-major transpose ----------------
__global__ void __launch_bounds__(256) emma_tr(const float* src, float* dst,
                                               int shift, int total)
{
  const int R = total >> shift;
  const int cmask = (1 << shift) - 1;
  for (int idx = blockIdx.x*256 + threadIdx.x; idx < total; idx += gridDim.x*256){
    int r = idx >> shift, c = idx & cmask;
    dst[(size_t)c * R + r] = src[idx];
  }
}

// ---------------- kernel 1a: scores, M zero, value-row norms, misc (v10 verbatim) ----------------
__global__ void __launch_bounds__(256) emma_k1a(
    const int* key_ids, const int* write_pos,
    const float* key_W, const float* value_W, const float* slot_keys,
    const float* lsr, int* wsI, float* wsF)
{
  const int wg = blockIdx.x, tid = threadIdx.x;
  if (wg < 256) {
    const int b = wg >> 3, chunk = wg & 7;
    __shared__ __align__(16) float s_kv[256];
    __shared__ float red[256];
    float v = key_W[key_ids[b]*256 + tid];
    red[tid] = v*v; __syncthreads();
    for (int st=128; st; st>>=1){ if (tid<st) red[tid]+=red[tid+st]; __syncthreads(); }
    float inv = 1.f/fmaxf(sqrtf(red[0]), 1e-12f);
    s_kv[tid] = v*inv;
    __syncthreads();
    const int lane = tid & 63, wv = tid >> 6;
    float4 kv4 = *(const float4*)(s_kv + lane*4);
    for (int slot = chunk*512 + wv; slot < chunk*512 + 512; slot += 4){
      float4 sk = *(const float4*)(slot_keys + (size_t)slot*256 + lane*4);
      float p = kv4.x*sk.x + kv4.y*sk.y + kv4.z*sk.z + kv4.w*sk.w;
      #pragma unroll
      for (int m=32;m;m>>=1) p += __shfl_xor(p, m, 64);
      if (lane==0) wsF[OF_SCORES + b*4096 + slot] = p;
    }
  } else if (wg < 320) {
    const int j = wg - 256;
    for (int i=tid;i<16384;i+=256) wsF[OF_M + j*16384 + i] = 0.f;
  } else if (wg < 324) {
    const int row = (wg-320)*256 + tid;
    float ss=0.f; const float* r = value_W + (size_t)row*256;
    for (int k=0;k<256;k++){ float x=r[k]; ss += x*x; }
    wsF[OF_RNV + row] = 1.f/fmaxf(sqrtf(ss), 1e-12f);
  } else {
    for (int i=tid;i<2048;i+=256) wsI[i]=0;
    __shared__ int pres[32];
    if (tid<32){ int p=0; for (int bb=0;bb<32;bb++) if (write_pos[bb]==tid) p=1; pres[tid]=p; }
    __syncthreads();
    if (tid<32){
      int wp = write_pos[tid]; float f=1.f;
      for (int s=wp+1;s<32;s++) if (pres[s]) f *= 0.997f;
      wsF[OF_DFAC + tid] = f;
    }
    if (tid==0) wsF[OF_SCALE] = softplusf_(lsr[0]) + 1e-3f;
  }
}

// ---------------- kernel 1b: exact top-16 + softmax (v10 verbatim) ----------------
__global__ void __launch_bounds__(256) emma_k1b(int* wsI, float* wsF)
{
  const int b = blockIdx.x, tid = threadIdx.x;
  __shared__ float s_sc[4096];
  __shared__ float s_rv[256]; __shared__ int s_ri[256];
  __shared__ float s_tv[16];
  for (int n=tid;n<4096;n+=256) s_sc[n] = wsF[OF_SCORES + b*4096 + n];
  __syncthreads();
  for (int j=0;j<16;j++){
    float bv = -3.0e38f; int bi = 0x7fffffff;
    for (int n=tid;n<4096;n+=256){
      float v = s_sc[n];
      if (v > bv || (v == bv && n < bi)) { bv=v; bi=n; }
    }
    s_rv[tid]=bv; s_ri[tid]=bi; __syncthreads();
    for (int st=128; st; st>>=1){
      if (tid<st){
        float v2=s_rv[tid+st]; int i2=s_ri[tid+st];
        if (v2 > s_rv[tid] || (v2==s_rv[tid] && i2 < s_ri[tid])) { s_rv[tid]=v2; s_ri[tid]=i2; }
      }
      __syncthreads();
    }
    if (tid==0){
      s_tv[j] = s_rv[0];
      wsI[2048 + b*16 + j] = s_ri[0];
      s_sc[s_ri[0]] = -3.0e38f;
    }
    __syncthreads();
  }
  if (tid==0){
    float mx = s_tv[0], sum=0.f, w[16];
    for (int j=0;j<16;j++){ w[j]=expf(s_tv[j]-mx); sum+=w[j]; }
    for (int j=0;j<16;j++) wsF[OF_TOPW + b*16 + j] = w[j]/sum;
  }
}

// ---------------- kernel 2: persistent trajectory (all barriers fence-free) ----------------
__global__ void __launch_bounds__(256, 1) emma_k2(
    const int* tokens, const int* write_pos,
    const float* embed_W, const float* u_b1, const float* u_b2,
    const float* l_b, const float* l_bt, const float* h0,
    int* wsI, float* wsF)
{
  const int g = blockIdx.x & 7;
  const int w = blockIdx.x >> 3;
  const int tid = threadIdx.x;
  int* flags = wsI + g*32;
  int epoch = 0;

  float* Z  = wsF + OF_Z;
  float* T  = wsF + OF_T;
  float* CP = wsF + OF_CP;
  float* G  = wsF + OF_G;
  float* TA = wsF + OF_TAU;
  float* H  = wsF + OF_H;
  float* ZS = wsF + OF_ZS;
  float* HS = wsF + OF_HS;

  __shared__ __align__(16) float4 ldsA[32*129];   // W1ZT cols [w*32, w*32+32)
  __shared__ __align__(16) float4 ldsB[32*129];   // W2T cols [(w&15)*32,+32), k-half (w>>4)
  __shared__ __align__(16) float zstage[4*520];   // group activations [4][520-pad]
  __shared__ __align__(16) float tstage[4*520];   // group t-half [4][520-pad]

  // ---- stage per-WG DEQ weight slices into LDS (once) ----
  {
    const float* gA = wsF + OF_W1ZT + (size_t)(w*32)*512;
    const float* gB = wsF + OF_W2T  + (size_t)((w&15)*32)*1024 + (size_t)(w>>4)*512;
    for (int idx4 = tid; idx4 < 4096; idx4 += 256){
      int ci = idx4 >> 7, j = idx4 & 127;
      ldsA[ci*129 + j] = *(const float4*)(gA + (size_t)ci*512  + 4*j);
      ldsB[ci*129 + j] = *(const float4*)(gB + (size_t)ci*1024 + 4*j);
    }
  }

  // per-thread loop-invariant constants
  const int rA  = tid >> 5;            // valid for tid<128 phases
  const int bA  = g*4 + (rA & 3);
  const int ciA = tid & 31;
  const int cA  = w*32 + ciA;          // phase A output col
  const int c2B = (w&15)*32 + ciA;     // phase B output col
  const int kh  = w >> 4;              // phase B k-half
  float b2half = 0.f; int znr = 0, znc = 0;
  if (tid < 64){ int idx = w*64 + tid; znr = idx>>9; znc = idx&511; b2half = 0.5f*u_b2[znc]; }

  // ---- preamble: z=0, h=h0 | c_pre for step 0 (all shared writes sc1) ----
  if (w < 16) {
    int idx = w*256 + tid;
    if (idx < 2048) { int r=idx>>9, c=idx&511; cstf(&Z[(g*4+r)*512 + c], 0.f); }
    else { int i2=idx-2048; int r=i2>>9, c=i2&511; cstf(&H[(g*4+r)*512 + c], h0[c]); }
  } else {
    int r = tid>>6, b = g*4+r;
    int c = (w-16)*64 + (tid&63);
    int tok = tokens[b*64 + 0];
    const float* xr = embed_W + (size_t)tok*256;
    const float* wc = wsF + OF_W1XT + (size_t)c*256;
    float a0=0,a1=0,a2=0,a3=0;
    #pragma unroll 4
    for (int k=0;k<256;k+=4){
      float4 xv = *(const float4*)(xr + k);
      float4 wv = *(const float4*)(wc + k);
      a0 += xv.x*wv.x; a1 += xv.y*wv.y; a2 += xv.z*wv.z; a3 += xv.w*wv.w;
    }
    cstf(&CP[b*1024 + c], u_b1[c] + ((a0+a1)+(a2+a3)));
  }
  lbar(flags, w, epoch);

  for (int s=0;s<32;s++){
    // CP fixed across the 8 DEQ iters — hoist (sc1; lbar precedes).
    float cpv = (tid < 128) ? cldf(&CP[bA*1024 + cA]) : 0.f;
    for (int i=0;i<8;i++){
      float* zc = Z + (i&1)*16384;
      float* zn = Z + ((i&1)^1)*16384;
      // stage this group's z global(LLC)->LDS, coherent scalar loads
      #pragma unroll
      for (int k=0;k<8;k++){
        int idx = k*256 + tid;
        int r = idx>>9, c = idx&511;
        zstage[r*520 + c] = cldf(&zc[g*2048 + idx]);
      }
      __syncthreads();
      // ---- phase A: t = tanh(z@W1z + c_pre); also pre-bias z_next
      if (tid < 128) {
        const float4* wc4 = ldsA + ciA*129;
        const float*  zr  = zstage + rA*520;
        float a0=0,a1=0,a2=0,a3=0;
        #pragma unroll 8
        for (int j=0;j<128;j++){
          float4 wv = wc4[j];
          float4 zv = *(const float4*)(zr + 4*j);
          a0 += zv.x*wv.x; a1 += zv.y*wv.y; a2 += zv.z*wv.z; a3 += zv.w*wv.w;
        }
        cstf(&T[bA*1024 + cA], tanhf(cpv + (a0+a1)+(a2+a3)));
      }
      if (tid < 64) {
        cstf(&zn[(g*4+znr)*512 + znc], zstage[znr*520 + znc] + b2half);
      }
      lbar(flags, w, epoch);
      // stage this group's t k-half global(LLC)->LDS, coherent scalar loads
      #pragma unroll
      for (int k=0;k<8;k++){
        int idx = k*256 + tid;
        int r = idx>>9, c = idx&511;
        tstage[r*520 + c] = cldf(&T[(size_t)(g*4+r)*1024 + kh*512 + c]);
      }
      __syncthreads();
      // ---- phase B: z_next += 0.5*(t@W2), split-K 2-way across wgs via atomics
      if (tid < 128) {
        const float4* wc4 = ldsB + ciA*129;
        const float*  tr  = tstage + rA*520;
        float a0=0,a1=0,a2=0,a3=0;
        #pragma unroll 8
        for (int j=0;j<128;j++){
          float4 wv = wc4[j];
          float4 tv = *(const float4*)(tr + 4*j);
          a0 += tv.x*wv.x; a1 += tv.y*wv.y; a2 += tv.z*wv.z; a3 += tv.w*wv.w;
        }
        atomicAdd(&zn[bA*512 + c2B], 0.5f*((a0+a1)+(a2+a3)));
      }
      if (i==7 && tid>=128) {  // init liquid pre-act buffers with biases (sc1 -> LLC)
        int idx = w*128 + (tid-128);
        if (idx < 2048){ int r=idx>>9, c=idx&511; cstf(&G[(g*4+r)*512+c], l_b[c]); }
        else { int i2=idx-2048; int r=i2>>9, c=i2&511; cstf(&TA[(g*4+r)*512+c], l_bt[c]); }
      }
      lbar(flags, w, epoch);
    }
    // ---- L1: liquid gate/tau pre-activations, split-K via atomics.
    // Input rows (final Z for kh=0, H for kh=1) staged LDS via sc1; weight
    // columns stay NORMAL cached loads (read-only, L2-resident — never
    // invalidated now that no heavy fences exist).
    #pragma unroll
    for (int k=0;k<8;k++){
      int idx = k*256 + tid;
      int r = idx>>9, c = idx&511;
      const float* src = (kh==0) ? &Z[(size_t)(g*4+r)*512 + c] : &H[(size_t)(g*4+r)*512 + c];
      zstage[r*520 + c] = cldf(src);
    }
    __syncthreads();
    {
      int sub = tid>>7, l = tid&127;
      int r = l>>5, b = g*4+r;
      int c2 = (w&15)*32 + (l&31);
      const float* inrow = zstage + r*520;
      const float* Wc = (sub ? (kh==0 ? wsF+OF_LWTIT : wsF+OF_LWTHT)
                             : (kh==0 ? wsF+OF_LWIT  : wsF+OF_LWHT)) + (size_t)c2*512;
      float a0=0,a1=0,a2=0,a3=0;
      #pragma unroll 4
      for (int k=0;k<512;k+=4){
        float4 iv = *(const float4*)(inrow + k);
        float4 wv = *(const float4*)(Wc + k);
        a0 += iv.x*wv.x; a1 += iv.y*wv.y; a2 += iv.z*wv.z; a3 += iv.w*wv.w;
      }
      atomicAdd(sub ? &TA[b*512+c2] : &G[b*512+c2], (a0+a1)+(a2+a3));
    }
    lbar(flags, w, epoch);
    // ---- L2: h update (+snapshots at write step) | c_pre for next step (all sc1) ----
    if (w < 16) {
      if (tid < 128) {
        int r = tid>>5, b = g*4+r;
        int c2 = w*32 + (tid&31);
        float gv = tanhf(cldf(&G[b*512+c2]));
        float tv = softplusf_(cldf(&TA[b*512+c2])) + 1.0f;
        float hv = cldf(&H[b*512+c2]);
        float hn = hv + (gv - hv)/tv;
        cstf(&H[b*512+c2], hn);
        if (write_pos[b] == s) {
          cstf(&ZS[b*512+c2], cldf(&Z[b*512+c2]));
          cstf(&HS[b*512+c2], hn);
        }
      }
    } else if (s+1 < 32) {
      int r = tid>>6, b = g*4+r;
      int c = (w-16)*64 + (tid&63);
      int tok = tokens[b*64 + s+1];
      const float* xr = embed_W + (size_t)tok*256;
      const float* wc = wsF + OF_W1XT + (size_t)c*256;
      float a0=0,a1=0,a2=0,a3=0;
      #pragma unroll 4
      for (int k=0;k<256;k+=4){
        float4 xv = *(const float4*)(xr + k);
        float4 wv = *(const float4*)(wc + k);
        a0 += xv.x*wv.x; a1 += xv.y*wv.y; a2 += xv.z*wv.z; a3 += xv.w*wv.w;
      }
      cstf(&CP[b*1024 + c], u_b1[c] + ((a0+a1)+(a2+a3)));
    }
    lbar(flags, w, epoch);
  }
}

// ---------------- kernel 3: v_pred + decay-weighted scatter into M (v10 verbatim) ----------------
__global__ void __launch_bounds__(256) emma_k3(const float* z2v_W, const float* z2v_b,
                                               int* wsI, float* wsF)
{
  const int b = blockIdx.x, c = threadIdx.x;
  const float* zs = wsF + OF_ZS + b*512;
  const float* hs = wsF + OF_HS + b*512;
  float acc = z2v_b[c];
  for (int k=0;k<512;k++) acc += zs[k]*z2v_W[k*256 + c];
  for (int k=0;k<512;k++) acc += hs[k]*z2v_W[(512+k)*256 + c];
  __shared__ float red[256];
  red[c]=acc*acc; __syncthreads();
  for (int st=128; st; st>>=1){ if (c<st) red[c]+=red[c+st]; __syncthreads(); }
  float inv = 1.f/fmaxf(sqrtf(red[0]),1e-12f);
  float vp = acc*inv;
  float f = wsF[OF_DFAC + b];
  for (int j=0;j<16;j++){
    int slot = wsI[2048 + b*16 + j];
    float wj = wsF[OF_TOPW + b*16 + j];
    atomicAdd(&wsF[OF_M + (size_t)slot*256 + c], f*wj*vp);
  }
}

// ---------------- kernel 4: v_mem read, normalize, logits (v10 verbatim) ----------------
__global__ void __launch_bounds__(256) emma_k4(const float* value_W, int* wsI, float* wsF,
                                               float* out)
{
  const int b = blockIdx.x, c = threadIdx.x;
  float m = 0.f;
  for (int j=0;j<16;j++){
    int slot = wsI[2048 + b*16 + j];
    m += wsF[OF_TOPW + b*16 + j] * wsF[OF_M + (size_t)slot*256 + c];
  }
  __shared__ float red[256];
  __shared__ float vn[256];
  red[c]=m*m; __syncthreads();
  for (int st=128; st; st>>=1){ if (c<st) red[c]+=red[c+st]; __syncthreads(); }
  float inv = 1.f/fmaxf(sqrtf(red[0]),1e-12f);
  vn[c] = m*inv;
  __syncthreads();
  float scale = wsF[OF_SCALE];
  for (int q=0;q<4;q++){
    int val = q*256 + c;
    const float* row = value_W + (size_t)val*256;
    float d0=0,d1=0,d2=0,d3=0;
    #pragma unroll 4
    for (int k=0;k<256;k+=4){
      float4 rv = *(const float4*)(row + k);
      d0 += vn[k+0]*rv.x; d1 += vn[k+1]*rv.y; d2 += vn[k+2]*rv.z; d3 += vn[k+3]*rv.w;
    }
    out[b*1024 + val] = scale * wsF[OF_RNV + val] * ((d0+d1)+(d2+d3));
  }
}

extern "C" void kernel_launch(void* const* d_in, const int* in_sizes, int n_in,
                              void* d_out, int out_size, void* d_ws, size_t ws_size,
                              hipStream_t stream)
{
  const int*   tokens    = (const int*)  d_in[0];
  const int*   key_ids   = (const int*)  d_in[1];
  const int*   write_pos = (const int*)  d_in[2];
  const float* embed_W   = (const float*)d_in[5];
  const float* key_W     = (const float*)d_in[6];
  const float* value_W   = (const float*)d_in[7];
  const float* u_W1      = (const float*)d_in[8];
  const float* u_b1      = (const float*)d_in[9];
  const float* u_W2      = (const float*)d_in[10];
  const float* u_b2      = (const float*)d_in[11];
  const float* l_Wi      = (const float*)d_in[12];
  const float* l_Wh      = (const float*)d_in[13];
  const float* l_b       = (const float*)d_in[14];
  const float* l_Wti     = (const float*)d_in[15];
  const float* l_Wth     = (const float*)d_in[16];
  const float* l_bt      = (const float*)d_in[17];
  const float* h0        = (const float*)d_in[18];
  const float* z2v_W     = (const float*)d_in[19];
  const float* z2v_b     = (const float*)d_in[20];
  const float* lsr       = (const float*)d_in[21];
  const float* slot_keys = (const float*)d_in[22];

  int*   wsI = (int*)d_ws;
  float* wsF = (float*)((char*)d_ws + 16384);
  float* out = (float*)d_out;

  hipLaunchKernelGGL(emma_k1a, dim3(325), dim3(256), 0, stream,
                     key_ids, write_pos, key_W, value_W, slot_keys, lsr, wsI, wsF);
  hipLaunchKernelGGL(emma_k1b, dim3(32), dim3(256), 0, stream, wsI, wsF);
  // weight transposes (row-major [R][1<<shift] -> col-major):
  hipLaunchKernelGGL(emma_tr, dim3(512), dim3(256), 0, stream, u_W1,            wsF+OF_W1ZT, 10, 512*1024);
  hipLaunchKernelGGL(emma_tr, dim3(512), dim3(256), 0, stream, u_W1 + 512*1024, wsF+OF_W1XT, 10, 256*1024);
  hipLaunchKernelGGL(emma_tr, dim3(512), dim3(256), 0, stream, u_W2,            wsF+OF_W2T,   9, 1024*512);
  hipLaunchKernelGGL(emma_tr, dim3(512), dim3(256), 0, stream, l_Wi,            wsF+OF_LWIT,  9, 512*512);
  hipLaunchKernelGGL(emma_tr, dim3(512), dim3(256), 0, stream, l_Wh,            wsF+OF_LWHT,  9, 512*512);
  hipLaunchKernelGGL(emma_tr, dim3(512), dim3(256), 0, stream, l_Wti,           wsF+OF_LWTIT, 9, 512*512);
  hipLaunchKernelGGL(emma_tr, dim3(512), dim3(256), 0, stream, l_Wth,           wsF+OF_LWTHT, 9, 512*512);
  {
    void* args[] = { (void*)&tokens, (void*)&write_pos, (void*)&embed_W,
                     (void*)&u_b1, (void*)&u_b2, (void*)&l_b, (void*)&l_bt, (void*)&h0,
                     (void*)&wsI, (void*)&wsF };
    hipLaunchCooperativeKernel(reinterpret_cast<void*>(emma_k2), dim3(256), dim3(256),
                               args, 0, stream);
  }
  hipLaunchKernelGGL(emma_k3, dim3(32), dim3(256), 0, stream, z2v_W, z2v_b, wsI, wsF);
  hipLaunchKernelGGL(emma_k4, dim3(32), dim3(256), 0, stream, value_W, wsI, wsF, out);
}

// Round 6
// 4171.925 us; speedup vs baseline: 2.6228x; 1.0437x over previous
//
#include <hip/hip_runtime.h>
#include <math.h>

// EMMA_38792144617759 v14 — BISECT round 2. v12/v13 (both FAILED, identical
// absmax 0.748) shared two mechanism clusters: (A) T->LDS tile + K=32-slice
// dotB; (B) triple-buffer + zero-ahead + atomic-folded base. v14 = v11
// (PASSED, 4.35ms) verbatim + cluster A ONLY: phase A writes T to an LDS tile
// (tl) instead of global T; phase B becomes the K-slice dotB (each WG adds its
// own 32 T-cols' contribution, 0.5*t@W2 slice, via atomicAdd into zn — NO base
// term, since v11's proven phase-A pre-bias cstf (zn = z + 0.5*b2) is kept,
// ordered against the atomics by the retained A->B lbar). Double z buffer,
// barrier count (16/step, 577 total), L1/L2/preamble/CP: v11 verbatim.
// If v14 passes -> v12/v13 bug is in cluster B. If it fails -> cluster A.

#define NGRP 8
#define WPG  32

// ---- workspace float offsets (wsF = d_ws + 16KB; first 16KB is int region) ----
#define OF_SCALE  0
#define OF_DFAC   32
#define OF_RNV    64
#define OF_TOPW   1088
#define OF_SCORES 1600      // 32*4096
#define OF_Z      132672    // 2*32*512 (double-buffered z, v11 layout)
#define OF_T      165440    // (unused in v14; T lives in LDS now)
#define OF_CP     198208    // 32*1024 (global CP, v11 path)
#define OF_G      230976    // 32*512
#define OF_TAU    247360    // 32*512
#define OF_H      263744    // 32*512
#define OF_ZS     280128    // 32*512
#define OF_HS     296512    // 32*512
#define OF_M      312896    // 4096*256
// transposed weight copies (filled by emma_tr before k2):
#define OF_W1ZT   1361472   // [1024 c][512 k]  = u_W1[k][c], k<512
#define OF_W1XT   1885760   // [1024 c][256 k]  = u_W1[512+k][c]
#define OF_W2T    2147904   // [512 c][1024 k]  = u_W2[k][c]
#define OF_LWIT   2672192   // [512 c][512 k]   = l_Wi[k][c]
#define OF_LWHT   2934336   // [512 c][512 k]   = l_Wh[k][c]
#define OF_LWTIT  3196480   // [512 c][512 k]   = l_Wti[k][c]
#define OF_LWTHT  3458624   // [512 c][512 k]   = l_Wth[k][c]
// wsI: [0..2048) barrier flags region (g*32+w used), [2048..2560) top_i

__device__ __forceinline__ float softplusf_(float x){ return x > 20.f ? x : log1pf(expf(x)); }

__device__ __forceinline__ float cldf(const float* p){
  return __hip_atomic_load(p, __ATOMIC_RELAXED, __HIP_MEMORY_SCOPE_AGENT);
}
__device__ __forceinline__ void cstf(float* p, float v){
  __hip_atomic_store(p, v, __ATOMIC_RELAXED, __HIP_MEMORY_SCOPE_AGENT);
}

// Light fence-free barrier (PROVEN v10/v11): all cross-WG data moves via sc1
// (LLC) ops; vmcnt(0) drains this wave's sc1 stores/atomics before the flag.
__device__ __forceinline__ void lbar(int* flags, int w, int& epoch){
  asm volatile("s_waitcnt vmcnt(0)" ::: "memory");
  __syncthreads();
  epoch++;
  if (threadIdx.x == 0)
    __hip_atomic_store(&flags[w], epoch, __ATOMIC_RELAXED, __HIP_MEMORY_SCOPE_AGENT);
  if (threadIdx.x < 32){
    while (__hip_atomic_load(&flags[threadIdx.x], __ATOMIC_RELAXED,
                             __HIP_MEMORY_SCOPE_AGENT) < epoch)
      __builtin_amdgcn_s_sleep(1);
  }
  asm volatile("" ::: "memory");
  __syncthreads();
}

// ---------------- kernel 0: generic row-major -> col-major transpose ----------------
__global__ void __launch_bounds__(256) emma_tr(const float* src, float* dst,
                                               int shift, int total)
{
  const int R = total >> shift;
  const int cmask = (1 << shift) - 1;
  for (int idx = blockIdx.x*256 + threadIdx.x; idx < total; idx += gridDim.x*256){
    int r = idx >> shift, c = idx & cmask;
    dst[(size_t)c * R + r] = src[idx];
  }
}

// ---------------- kernel 1a: scores, M zero, value-row norms, misc (v11 verbatim) ----------------
__global__ void __launch_bounds__(256) emma_k1a(
    const int* key_ids, const int* write_pos,
    const float* key_W, const float* value_W, const float* slot_keys,
    const float* lsr, int* wsI, float* wsF)
{
  const int wg = blockIdx.x, tid = threadIdx.x;
  if (wg < 256) {
    const int b = wg >> 3, chunk = wg & 7;
    __shared__ __align__(16) float s_kv[256];
    __shared__ float red[256];
    float v = key_W[key_ids[b]*256 + tid];
    red[tid] = v*v; __syncthreads();
    for (int st=128; st; st>>=1){ if (tid<st) red[tid]+=red[tid+st]; __syncthreads(); }
    float inv = 1.f/fmaxf(sqrtf(red[0]), 1e-12f);
    s_kv[tid] = v*inv;
    __syncthreads();
    const int lane = tid & 63, wv = tid >> 6;
    float4 kv4 = *(const float4*)(s_kv + lane*4);
    for (int slot = chunk*512 + wv; slot < chunk*512 + 512; slot += 4){
      float4 sk = *(const float4*)(slot_keys + (size_t)slot*256 + lane*4);
      float p = kv4.x*sk.x + kv4.y*sk.y + kv4.z*sk.z + kv4.w*sk.w;
      #pragma unroll
      for (int m=32;m;m>>=1) p += __shfl_xor(p, m, 64);
      if (lane==0) wsF[OF_SCORES + b*4096 + slot] = p;
    }
  } else if (wg < 320) {
    const int j = wg - 256;
    for (int i=tid;i<16384;i+=256) wsF[OF_M + j*16384 + i] = 0.f;
  } else if (wg < 324) {
    const int row = (wg-320)*256 + tid;
    float ss=0.f; const float* r = value_W + (size_t)row*256;
    for (int k=0;k<256;k++){ float x=r[k]; ss += x*x; }
    wsF[OF_RNV + row] = 1.f/fmaxf(sqrtf(ss), 1e-12f);
  } else {
    for (int i=tid;i<2048;i+=256) wsI[i]=0;
    __shared__ int pres[32];
    if (tid<32){ int p=0; for (int bb=0;bb<32;bb++) if (write_pos[bb]==tid) p=1; pres[tid]=p; }
    __syncthreads();
    if (tid<32){
      int wp = write_pos[tid]; float f=1.f;
      for (int s=wp+1;s<32;s++) if (pres[s]) f *= 0.997f;
      wsF[OF_DFAC + tid] = f;
    }
    if (tid==0) wsF[OF_SCALE] = softplusf_(lsr[0]) + 1e-3f;
  }
}

// ---------------- kernel 1b: exact top-16 + softmax (v11 verbatim) ----------------
__global__ void __launch_bounds__(256) emma_k1b(int* wsI, float* wsF)
{
  const int b = blockIdx.x, tid = threadIdx.x;
  __shared__ float s_sc[4096];
  __shared__ float s_rv[256]; __shared__ int s_ri[256];
  __shared__ float s_tv[16];
  for (int n=tid;n<4096;n+=256) s_sc[n] = wsF[OF_SCORES + b*4096 + n];
  __syncthreads();
  for (int j=0;j<16;j++){
    float bv = -3.0e38f; int bi = 0x7fffffff;
    for (int n=tid;n<4096;n+=256){
      float v = s_sc[n];
      if (v > bv || (v == bv && n < bi)) { bv=v; bi=n; }
    }
    s_rv[tid]=bv; s_ri[tid]=bi; __syncthreads();
    for (int st=128; st; st>>=1){
      if (tid<st){
        float v2=s_rv[tid+st]; int i2=s_ri[tid+st];
        if (v2 > s_rv[tid] || (v2==s_rv[tid] && i2 < s_ri[tid])) { s_rv[tid]=v2; s_ri[tid]=i2; }
      }
      __syncthreads();
    }
    if (tid==0){
      s_tv[j] = s_rv[0];
      wsI[2048 + b*16 + j] = s_ri[0];
      s_sc[s_ri[0]] = -3.0e38f;
    }
    __syncthreads();
  }
  if (tid==0){
    float mx = s_tv[0], sum=0.f, w[16];
    for (int j=0;j<16;j++){ w[j]=expf(s_tv[j]-mx); sum+=w[j]; }
    for (int j=0;j<16;j++) wsF[OF_TOPW + b*16 + j] = w[j]/sum;
  }
}

// ---------------- kernel 2: persistent trajectory (v11 + LDS-T K-slice dotB) ----------------
__global__ void __launch_bounds__(256, 1) emma_k2(
    const int* tokens, const int* write_pos,
    const float* embed_W, const float* u_b1, const float* u_b2,
    const float* l_b, const float* l_bt, const float* h0,
    int* wsI, float* wsF)
{
  const int g = blockIdx.x & 7;
  const int w = blockIdx.x >> 3;
  const int tid = threadIdx.x;
  int* flags = wsI + g*32;
  int epoch = 0;

  float* Z  = wsF + OF_Z;
  float* CP = wsF + OF_CP;
  float* G  = wsF + OF_G;
  float* TA = wsF + OF_TAU;
  float* H  = wsF + OF_H;
  float* ZS = wsF + OF_ZS;
  float* HS = wsF + OF_HS;

  __shared__ __align__(16) float4 ldsA[32*129];   // W1ZT cols [w*32,+32), 129-f4 pad (v11)
  __shared__ __align__(16) float4 ldsB[4096];     // W2 rows k in [w*32,+32) x 512 c2, XOR-swz
  __shared__ __align__(16) float zstage[4*520];   // group activations [4][520-pad]
  __shared__ __align__(16) float tl[4*36];        // T tile [4 rows][32 local cols, pad 36]

  // ---- stage per-WG weight slices into LDS (once) ----
  {
    const float* gA = wsF + OF_W1ZT + (size_t)(w*32)*512;
    const float* gB = wsF + OF_W2T;
    for (int idx4 = tid; idx4 < 4096; idx4 += 256){
      { int ci = idx4 >> 7, j = idx4 & 127;
        ldsA[ci*129 + j] = *(const float4*)(gA + (size_t)ci*512 + 4*j); }
      { int c2 = idx4 >> 3, j4 = idx4 & 7;
        ldsB[c2*8 + (j4 ^ (c2 & 7))] =
            *(const float4*)(gB + (size_t)c2*1024 + w*32 + 4*j4); }
    }
  }

  // per-thread loop-invariant constants (v11 names)
  const int rA  = tid >> 5;            // valid for tid<128 phases
  const int bA  = g*4 + (rA & 3);
  const int ciA = tid & 31;
  const int cA  = w*32 + ciA;          // dotA output col (global k index)
  const int r3  = tid >> 6;            // dotB row
  const int c2l = tid & 63;            // dotB col residue
  const int kh  = w >> 4;              // L1 k-half
  float b2half = 0.f; int znr = 0, znc = 0;
  if (tid < 64){ int idx = w*64 + tid; znr = idx>>9; znc = idx&511; b2half = 0.5f*u_b2[znc]; }

  // ---- preamble: z=0, h=h0 | c_pre for step 0 (v11 verbatim) ----
  if (w < 16) {
    int idx = w*256 + tid;
    if (idx < 2048) cstf(&Z[g*2048 + idx], 0.f);
    else { int i2=idx-2048; int r=i2>>9, c=i2&511; cstf(&H[(g*4+r)*512 + c], h0[c]); }
  } else {
    int r = tid>>6, b = g*4+r;
    int c = (w-16)*64 + (tid&63);
    int tok = tokens[b*64 + 0];
    const float* xr = embed_W + (size_t)tok*256;
    const float* wc = wsF + OF_W1XT + (size_t)c*256;
    float a0=0,a1=0,a2=0,a3=0;
    #pragma unroll 4
    for (int k=0;k<256;k+=4){
      float4 xv = *(const float4*)(xr + k);
      float4 wv = *(const float4*)(wc + k);
      a0 += xv.x*wv.x; a1 += xv.y*wv.y; a2 += xv.z*wv.z; a3 += xv.w*wv.w;
    }
    cstf(&CP[b*1024 + c], u_b1[c] + ((a0+a1)+(a2+a3)));
  }
  lbar(flags, w, epoch);

  for (int s=0;s<32;s++){
    // CP fixed across the 8 DEQ iters — hoist (sc1; lbar precedes). v11 path.
    float cpv = (tid < 128) ? cldf(&CP[bA*1024 + cA]) : 0.f;
    for (int i=0;i<8;i++){
      float* zc = Z + (i&1)*16384;
      float* zn = Z + ((i&1)^1)*16384;
      // stage z -> LDS (sc1 coherent loads, coalesced) — v11 verbatim
      #pragma unroll
      for (int k=0;k<8;k++){
        int idx = k*256 + tid;
        zstage[(idx>>9)*520 + (idx&511)] = cldf(&zc[g*2048 + idx]);
      }
      __syncthreads();
      // ---- phase A: dotA -> tl (LDS); pre-bias zn = z + 0.5*b2 (v11 verbatim)
      if (tid < 128) {
        const float4* wc4 = ldsA + ciA*129;
        const float*  zr  = zstage + rA*520;
        float a0=0,a1=0,a2=0,a3=0;
        #pragma unroll 8
        for (int j=0;j<128;j++){
          float4 wv = wc4[j];
          float4 zv = *(const float4*)(zr + 4*j);
          a0 += zv.x*wv.x; a1 += zv.y*wv.y; a2 += zv.z*wv.z; a3 += zv.w*wv.w;
        }
        tl[rA*36 + ciA] = tanhf(cpv + (a0+a1)+(a2+a3));
      }
      if (tid < 64) {
        cstf(&zn[(g*4+znr)*512 + znc], zstage[znr*520 + znc] + b2half);
      }
      lbar(flags, w, epoch);
      // ---- phase B: K=32-slice dotB from tl; atomicAdd 0.5*(t@W2 slice) into zn
      {
        const float* trow = tl + r3*36;
        float accs[8] = {0.f,0.f,0.f,0.f,0.f,0.f,0.f,0.f};
        #pragma unroll
        for (int j4=0;j4<8;j4++){
          float4 tv = *(const float4*)(trow + 4*j4);
          int o = c2l*8 + (j4 ^ (c2l & 7));
          #pragma unroll
          for (int cc=0;cc<8;cc++){
            float4 wv = ldsB[o + 512*cc];
            accs[cc] += tv.x*wv.x + tv.y*wv.y + tv.z*wv.z + tv.w*wv.w;
          }
        }
        float* zrow = &zn[(g*4+r3)*512];
        #pragma unroll
        for (int cc=0;cc<8;cc++){
          atomicAdd(&zrow[c2l + 64*cc], 0.5f*accs[cc]);
        }
      }
      if (i==7 && tid>=128) {  // init liquid pre-act buffers with biases (v11 verbatim)
        int idx = w*128 + (tid-128);
        if (idx < 2048){ int r=idx>>9, c=idx&511; cstf(&G[(g*4+r)*512+c], l_b[c]); }
        else { int i2=idx-2048; int r=i2>>9, c=i2&511; cstf(&TA[(g*4+r)*512+c], l_bt[c]); }
      }
      lbar(flags, w, epoch);
    }
    // ---- L1: liquid gate/tau pre-activations (v11 verbatim; final z in buffer 0) ----
    #pragma unroll
    for (int k=0;k<8;k++){
      int idx = k*256 + tid; int r = idx>>9, c = idx&511;
      const float* src = (kh==0) ? &Z[g*2048 + idx] : &H[g*2048 + idx];
      zstage[r*520 + c] = cldf(src);
    }
    __syncthreads();
    {
      int sub = tid>>7, l = tid&127;
      int r = l>>5, b = g*4+r;
      int c2 = (w&15)*32 + (l&31);
      const float* inrow = zstage + r*520;
      const float* Wc = (sub ? (kh==0 ? wsF+OF_LWTIT : wsF+OF_LWTHT)
                             : (kh==0 ? wsF+OF_LWIT  : wsF+OF_LWHT)) + (size_t)c2*512;
      float a0=0,a1=0,a2=0,a3=0;
      #pragma unroll 8
      for (int k=0;k<512;k+=4){
        float4 iv = *(const float4*)(inrow + k);
        float4 wv = *(const float4*)(Wc + k);
        a0 += iv.x*wv.x; a1 += iv.y*wv.y; a2 += iv.z*wv.z; a3 += iv.w*wv.w;
      }
      atomicAdd(sub ? &TA[b*512+c2] : &G[b*512+c2], (a0+a1)+(a2+a3));
    }
    lbar(flags, w, epoch);
    // ---- L2: h update (+snapshots at write step) | c_pre for next step (v11 verbatim) ----
    if (w < 16) {
      if (tid < 128) {
        int r = tid>>5, b = g*4+r;
        int c2 = w*32 + (tid&31);
        float gv = tanhf(cldf(&G[b*512+c2]));
        float tv = softplusf_(cldf(&TA[b*512+c2])) + 1.0f;
        float hv = cldf(&H[b*512+c2]);
        float hn = hv + (gv - hv)/tv;
        cstf(&H[b*512+c2], hn);
        if (write_pos[b] == s) {
          cstf(&ZS[b*512+c2], cldf(&Z[b*512+c2]));
          cstf(&HS[b*512+c2], hn);
        }
      }
    } else if (s+1 < 32) {
      int r = tid>>6, b = g*4+r;
      int c = (w-16)*64 + (tid&63);
      int tok = tokens[b*64 + s+1];
      const float* xr = embed_W + (size_t)tok*256;
      const float* wc = wsF + OF_W1XT + (size_t)c*256;
      float a0=0,a1=0,a2=0,a3=0;
      #pragma unroll 4
      for (int k=0;k<256;k+=4){
        float4 xv = *(const float4*)(xr + k);
        float4 wv = *(const float4*)(wc + k);
        a0 += xv.x*wv.x; a1 += xv.y*wv.y; a2 += xv.z*wv.z; a3 += xv.w*wv.w;
      }
      cstf(&CP[b*1024 + c], u_b1[c] + ((a0+a1)+(a2+a3)));
    }
    lbar(flags, w, epoch);
  }
}

// ---------------- kernel 3: v_pred + decay-weighted scatter into M (v11 verbatim) ----------------
__global__ void __launch_bounds__(256) emma_k3(const float* z2v_W, const float* z2v_b,
                                               int* wsI, float* wsF)
{
  const int b = blockIdx.x, c = threadIdx.x;
  const float* zs = wsF + OF_ZS + b*512;
  const float* hs = wsF + OF_HS + b*512;
  float acc = z2v_b[c];
  for (int k=0;k<512;k++) acc += zs[k]*z2v_W[k*256 + c];
  for (int k=0;k<512;k++) acc += hs[k]*z2v_W[(512+k)*256 + c];
  __shared__ float red[256];
  red[c]=acc*acc; __syncthreads();
  for (int st=128; st; st>>=1){ if (c<st) red[c]+=red[c+st]; __syncthreads(); }
  float inv = 1.f/fmaxf(sqrtf(red[0]),1e-12f);
  float vp = acc*inv;
  float f = wsF[OF_DFAC + b];
  for (int j=0;j<16;j++){
    int slot = wsI[2048 + b*16 + j];
    float wj = wsF[OF_TOPW + b*16 + j];
    atomicAdd(&wsF[OF_M + (size_t)slot*256 + c], f*wj*vp);
  }
}

// ---------------- kernel 4: v_mem read, normalize, logits (v11 verbatim) ----------------
__global__ void __launch_bounds__(256) emma_k4(const float* value_W, int* wsI, float* wsF,
                                               float* out)
{
  const int b = blockIdx.x, c = threadIdx.x;
  float m = 0.f;
  for (int j=0;j<16;j++){
    int slot = wsI[2048 + b*16 + j];
    m += wsF[OF_TOPW + b*16 + j] * wsF[OF_M + (size_t)slot*256 + c];
  }
  __shared__ float red[256];
  __shared__ float vn[256];
  red[c]=m*m; __syncthreads();
  for (int st=128; st; st>>=1){ if (c<st) red[c]+=red[c+st]; __syncthreads(); }
  float inv = 1.f/fmaxf(sqrtf(red[0]),1e-12f);
  vn[c] = m*inv;
  __syncthreads();
  float scale = wsF[OF_SCALE];
  for (int q=0;q<4;q++){
    int val = q*256 + c;
    const float* row = value_W + (size_t)val*256;
    float d0=0,d1=0,d2=0,d3=0;
    #pragma unroll 4
    for (int k=0;k<256;k+=4){
      float4 rv = *(const float4*)(row + k);
      d0 += vn[k+0]*rv.x; d1 += vn[k+1]*rv.y; d2 += vn[k+2]*rv.z; d3 += vn[k+3]*rv.w;
    }
    out[b*1024 + val] = scale * wsF[OF_RNV + val] * ((d0+d1)+(d2+d3));
  }
}

extern "C" void kernel_launch(void* const* d_in, const int* in_sizes, int n_in,
                              void* d_out, int out_size, void* d_ws, size_t ws_size,
                              hipStream_t stream)
{
  const int*   tokens    = (const int*)  d_in[0];
  const int*   key_ids   = (const int*)  d_in[1];
  const int*   write_pos = (const int*)  d_in[2];
  const float* embed_W   = (const float*)d_in[5];
  const float* key_W     = (const float*)d_in[6];
  const float* value_W   = (const float*)d_in[7];
  const float* u_W1      = (const float*)d_in[8];
  const float* u_b1      = (const float*)d_in[9];
  const float* u_W2      = (const float*)d_in[10];
  const float* u_b2      = (const float*)d_in[11];
  const float* l_Wi      = (const float*)d_in[12];
  const float* l_Wh      = (const float*)d_in[13];
  const float* l_b       = (const float*)d_in[14];
  const float* l_Wti     = (const float*)d_in[15];
  const float* l_Wth     = (const float*)d_in[16];
  const float* l_bt      = (const float*)d_in[17];
  const float* h0        = (const float*)d_in[18];
  const float* z2v_W     = (const float*)d_in[19];
  const float* z2v_b     = (const float*)d_in[20];
  const float* lsr       = (const float*)d_in[21];
  const float* slot_keys = (const float*)d_in[22];

  int*   wsI = (int*)d_ws;
  float* wsF = (float*)((char*)d_ws + 16384);
  float* out = (float*)d_out;

  hipLaunchKernelGGL(emma_k1a, dim3(325), dim3(256), 0, stream,
                     key_ids, write_pos, key_W, value_W, slot_keys, lsr, wsI, wsF);
  hipLaunchKernelGGL(emma_k1b, dim3(32), dim3(256), 0, stream, wsI, wsF);
  // weight transposes (row-major [R][1<<shift] -> col-major):
  hipLaunchKernelGGL(emma_tr, dim3(512), dim3(256), 0, stream, u_W1,            wsF+OF_W1ZT, 10, 512*1024);
  hipLaunchKernelGGL(emma_tr, dim3(512), dim3(256), 0, stream, u_W1 + 512*1024, wsF+OF_W1XT, 10, 256*1024);
  hipLaunchKernelGGL(emma_tr, dim3(512), dim3(256), 0, stream, u_W2,            wsF+OF_W2T,   9, 1024*512);
  hipLaunchKernelGGL(emma_tr, dim3(512), dim3(256), 0, stream, l_Wi,            wsF+OF_LWIT,  9, 512*512);
  hipLaunchKernelGGL(emma_tr, dim3(512), dim3(256), 0, stream, l_Wh,            wsF+OF_LWHT,  9, 512*512);
  hipLaunchKernelGGL(emma_tr, dim3(512), dim3(256), 0, stream, l_Wti,           wsF+OF_LWTIT, 9, 512*512);
  hipLaunchKernelGGL(emma_tr, dim3(512), dim3(256), 0, stream, l_Wth,           wsF+OF_LWTHT, 9, 512*512);
  {
    void* args[] = { (void*)&tokens, (void*)&write_pos, (void*)&embed_W,
                     (void*)&u_b1, (void*)&u_b2, (void*)&l_b, (void*)&l_bt, (void*)&h0,
                     (void*)&wsI, (void*)&wsF };
    hipLaunchCooperativeKernel(reinterpret_cast<void*>(emma_k2), dim3(256), dim3(256),
                               args, 0, stream);
  }
  hipLaunchKernelGGL(emma_k3, dim3(32), dim3(256), 0, stream, z2v_W, z2v_b, wsI, wsF);
  hipLaunchKernelGGL(emma_k4, dim3(32), dim3(256), 0, stream, value_W, wsI, wsF, out);
}

// Round 7
// 3788.919 us; speedup vs baseline: 2.8880x; 1.1011x over previous
//
#include <hip/hip_runtime.h>
#include <math.h>

// EMMA_38792144617759 v15 — v14 (passed, 4.17ms) with two changes:
// (1) DEQ iters go single-lbar (577->321 phases) via DELTA-FOLD: target buffer
//     holds stale z_{i-1}; every WG's atomicAdd carries 0.5*slice + an equal
//     1/32 share of (z_i - z_{i-1} + 0.5*b2), with z_{i-1} carried in 8
//     per-thread registers (zp). Double buffer, NO zeroing, NO owner branch,
//     no pre-bias store -> the A->B barrier's only reason disappears.
//     Buffer 1 now zeroed in preamble (z_{-1}=0); zp init 0; parity makes
//     zn=z_7 at each later step's iter 0, matching the carried zp. v12/v13's
//     failed triple-buffer/zero-ahead protocol is NOT used.
// (2) ldsB layout transposed to [j4][c2] (no XOR): per wave-read 64 lanes hit
//     64 consecutive float4s (canonical pattern). v14's XOR layout caused the
//     6.7e7 SQ_LDS_BANK_CONFLICT (stride-8 aliasing: lanes sharing c2l&7 all
//     landed in one bank group).

#define NGRP 8
#define WPG  32

// ---- workspace float offsets (wsF = d_ws + 16KB; first 16KB is int region) ----
#define OF_SCALE  0
#define OF_DFAC   32
#define OF_RNV    64
#define OF_TOPW   1088
#define OF_SCORES 1600      // 32*4096
#define OF_Z      132672    // 2*32*512 (double-buffered z)
#define OF_CP     198208    // 32*1024 (global CP)
#define OF_G      230976    // 32*512
#define OF_TAU    247360    // 32*512
#define OF_H      263744    // 32*512
#define OF_ZS     280128    // 32*512
#define OF_HS     296512    // 32*512
#define OF_M      312896    // 4096*256
// transposed weight copies (filled by emma_tr before k2):
#define OF_W1ZT   1361472   // [1024 c][512 k]  = u_W1[k][c], k<512
#define OF_W1XT   1885760   // [1024 c][256 k]  = u_W1[512+k][c]
#define OF_W2T    2147904   // [512 c][1024 k]  = u_W2[k][c]
#define OF_LWIT   2672192   // [512 c][512 k]   = l_Wi[k][c]
#define OF_LWHT   2934336   // [512 c][512 k]   = l_Wh[k][c]
#define OF_LWTIT  3196480   // [512 c][512 k]   = l_Wti[k][c]
#define OF_LWTHT  3458624   // [512 c][512 k]   = l_Wth[k][c]
// wsI: [0..2048) barrier flags region (g*32+w used), [2048..2560) top_i

__device__ __forceinline__ float softplusf_(float x){ return x > 20.f ? x : log1pf(expf(x)); }

__device__ __forceinline__ float cldf(const float* p){
  return __hip_atomic_load(p, __ATOMIC_RELAXED, __HIP_MEMORY_SCOPE_AGENT);
}
__device__ __forceinline__ void cstf(float* p, float v){
  __hip_atomic_store(p, v, __ATOMIC_RELAXED, __HIP_MEMORY_SCOPE_AGENT);
}

// Light fence-free barrier (PROVEN v10/v11/v14): all cross-WG data moves via
// sc1 (LLC) ops; vmcnt(0) drains this wave's sc1 stores/atomics before the flag.
__device__ __forceinline__ void lbar(int* flags, int w, int& epoch){
  asm volatile("s_waitcnt vmcnt(0)" ::: "memory");
  __syncthreads();
  epoch++;
  if (threadIdx.x == 0)
    __hip_atomic_store(&flags[w], epoch, __ATOMIC_RELAXED, __HIP_MEMORY_SCOPE_AGENT);
  if (threadIdx.x < 32){
    while (__hip_atomic_load(&flags[threadIdx.x], __ATOMIC_RELAXED,
                             __HIP_MEMORY_SCOPE_AGENT) < epoch)
      __builtin_amdgcn_s_sleep(1);
  }
  asm volatile("" ::: "memory");
  __syncthreads();
}

// ---------------- kernel 0: generic row-major -> col-major transpose ----------------
__global__ void __launch_bounds__(256) emma_tr(const float* src, float* dst,
                                               int shift, int total)
{
  const int R = total >> shift;
  const int cmask = (1 << shift) - 1;
  for (int idx = blockIdx.x*256 + threadIdx.x; idx < total; idx += gridDim.x*256){
    int r = idx >> shift, c = idx & cmask;
    dst[(size_t)c * R + r] = src[idx];
  }
}

// ---------------- kernel 1a: scores, M zero, value-row norms, misc (v14 verbatim) ----------------
__global__ void __launch_bounds__(256) emma_k1a(
    const int* key_ids, const int* write_pos,
    const float* key_W, const float* value_W, const float* slot_keys,
    const float* lsr, int* wsI, float* wsF)
{
  const int wg = blockIdx.x, tid = threadIdx.x;
  if (wg < 256) {
    const int b = wg >> 3, chunk = wg & 7;
    __shared__ __align__(16) float s_kv[256];
    __shared__ float red[256];
    float v = key_W[key_ids[b]*256 + tid];
    red[tid] = v*v; __syncthreads();
    for (int st=128; st; st>>=1){ if (tid<st) red[tid]+=red[tid+st]; __syncthreads(); }
    float inv = 1.f/fmaxf(sqrtf(red[0]), 1e-12f);
    s_kv[tid] = v*inv;
    __syncthreads();
    const int lane = tid & 63, wv = tid >> 6;
    float4 kv4 = *(const float4*)(s_kv + lane*4);
    for (int slot = chunk*512 + wv; slot < chunk*512 + 512; slot += 4){
      float4 sk = *(const float4*)(slot_keys + (size_t)slot*256 + lane*4);
      float p = kv4.x*sk.x + kv4.y*sk.y + kv4.z*sk.z + kv4.w*sk.w;
      #pragma unroll
      for (int m=32;m;m>>=1) p += __shfl_xor(p, m, 64);
      if (lane==0) wsF[OF_SCORES + b*4096 + slot] = p;
    }
  } else if (wg < 320) {
    const int j = wg - 256;
    for (int i=tid;i<16384;i+=256) wsF[OF_M + j*16384 + i] = 0.f;
  } else if (wg < 324) {
    const int row = (wg-320)*256 + tid;
    float ss=0.f; const float* r = value_W + (size_t)row*256;
    for (int k=0;k<256;k++){ float x=r[k]; ss += x*x; }
    wsF[OF_RNV + row] = 1.f/fmaxf(sqrtf(ss), 1e-12f);
  } else {
    for (int i=tid;i<2048;i+=256) wsI[i]=0;
    __shared__ int pres[32];
    if (tid<32){ int p=0; for (int bb=0;bb<32;bb++) if (write_pos[bb]==tid) p=1; pres[tid]=p; }
    __syncthreads();
    if (tid<32){
      int wp = write_pos[tid]; float f=1.f;
      for (int s=wp+1;s<32;s++) if (pres[s]) f *= 0.997f;
      wsF[OF_DFAC + tid] = f;
    }
    if (tid==0) wsF[OF_SCALE] = softplusf_(lsr[0]) + 1e-3f;
  }
}

// ---------------- kernel 1b: exact top-16 + softmax (v14 verbatim) ----------------
__global__ void __launch_bounds__(256) emma_k1b(int* wsI, float* wsF)
{
  const int b = blockIdx.x, tid = threadIdx.x;
  __shared__ float s_sc[4096];
  __shared__ float s_rv[256]; __shared__ int s_ri[256];
  __shared__ float s_tv[16];
  for (int n=tid;n<4096;n+=256) s_sc[n] = wsF[OF_SCORES + b*4096 + n];
  __syncthreads();
  for (int j=0;j<16;j++){
    float bv = -3.0e38f; int bi = 0x7fffffff;
    for (int n=tid;n<4096;n+=256){
      float v = s_sc[n];
      if (v > bv || (v == bv && n < bi)) { bv=v; bi=n; }
    }
    s_rv[tid]=bv; s_ri[tid]=bi; __syncthreads();
    for (int st=128; st; st>>=1){
      if (tid<st){
        float v2=s_rv[tid+st]; int i2=s_ri[tid+st];
        if (v2 > s_rv[tid] || (v2==s_rv[tid] && i2 < s_ri[tid])) { s_rv[tid]=v2; s_ri[tid]=i2; }
      }
      __syncthreads();
    }
    if (tid==0){
      s_tv[j] = s_rv[0];
      wsI[2048 + b*16 + j] = s_ri[0];
      s_sc[s_ri[0]] = -3.0e38f;
    }
    __syncthreads();
  }
  if (tid==0){
    float mx = s_tv[0], sum=0.f, w[16];
    for (int j=0;j<16;j++){ w[j]=expf(s_tv[j]-mx); sum+=w[j]; }
    for (int j=0;j<16;j++) wsF[OF_TOPW + b*16 + j] = w[j]/sum;
  }
}

// ---------------- kernel 2: persistent trajectory (delta-fold single-lbar DEQ) ----------------
__global__ void __launch_bounds__(256, 1) emma_k2(
    const int* tokens, const int* write_pos,
    const float* embed_W, const float* u_b1, const float* u_b2,
    const float* l_b, const float* l_bt, const float* h0,
    int* wsI, float* wsF)
{
  const int g = blockIdx.x & 7;
  const int w = blockIdx.x >> 3;
  const int tid = threadIdx.x;
  int* flags = wsI + g*32;
  int epoch = 0;

  float* Z  = wsF + OF_Z;
  float* CP = wsF + OF_CP;
  float* G  = wsF + OF_G;
  float* TA = wsF + OF_TAU;
  float* H  = wsF + OF_H;
  float* ZS = wsF + OF_ZS;
  float* HS = wsF + OF_HS;

  __shared__ __align__(16) float4 ldsA[32*129];   // W1ZT cols [w*32,+32), 129-f4 pad
  __shared__ __align__(16) float4 ldsB[4096];     // W2 [j4][c2]: rows k in [w*32,+32)
  __shared__ __align__(16) float zstage[4*520];   // group activations [4][520-pad]
  __shared__ __align__(16) float tl[4*36];        // T tile [4 rows][32 local cols, pad 36]

  // ---- stage per-WG weight slices into LDS (once) ----
  {
    const float* gA = wsF + OF_W1ZT + (size_t)(w*32)*512;
    const float* gB = wsF + OF_W2T;
    for (int idx4 = tid; idx4 < 4096; idx4 += 256){
      { int ci = idx4 >> 7, j = idx4 & 127;
        ldsA[ci*129 + j] = *(const float4*)(gA + (size_t)ci*512 + 4*j); }
      { int j4 = idx4 >> 9, c2 = idx4 & 511;   // dst = j4*512 + c2 = idx4
        ldsB[idx4] = *(const float4*)(gB + (size_t)c2*1024 + w*32 + 4*j4); }
    }
  }

  // per-thread loop-invariant constants
  const int rA  = tid >> 5;            // valid for tid<128 phases
  const int bA  = g*4 + (rA & 3);
  const int ciA = tid & 31;
  const int cA  = w*32 + ciA;          // dotA output col (global k index)
  const int r3  = tid >> 6;            // dotB row
  const int c2l = tid & 63;            // dotB col residue
  const int kh  = w >> 4;              // L1 k-half
  float bh[8];                         // 0.5*b2 for this thread's 8 c2, /32 share applied later
  #pragma unroll
  for (int cc=0;cc<8;cc++) bh[cc] = 0.5f*u_b2[c2l + 64*cc];
  float zp[8] = {0.f,0.f,0.f,0.f,0.f,0.f,0.f,0.f};   // z_{i-1} carry (z_{-1}=0)

  // ---- preamble: z bufs 0 AND 1 = 0, h=h0 | c_pre for step 0 ----
  if (w < 16) {
    int idx = w*256 + tid;
    if (idx < 2048) cstf(&Z[g*2048 + idx], 0.f);
    else { int i2=idx-2048; int r=i2>>9, c=i2&511; cstf(&H[(g*4+r)*512 + c], h0[c]); }
  } else {
    { int idx = (w-16)*256 + tid;
      if (idx < 2048) cstf(&Z[16384 + g*2048 + idx], 0.f); }
    int r = tid>>6, b = g*4+r;
    int c = (w-16)*64 + (tid&63);
    int tok = tokens[b*64 + 0];
    const float* xr = embed_W + (size_t)tok*256;
    const float* wc = wsF + OF_W1XT + (size_t)c*256;
    float a0=0,a1=0,a2=0,a3=0;
    #pragma unroll 4
    for (int k=0;k<256;k+=4){
      float4 xv = *(const float4*)(xr + k);
      float4 wv = *(const float4*)(wc + k);
      a0 += xv.x*wv.x; a1 += xv.y*wv.y; a2 += xv.z*wv.z; a3 += xv.w*wv.w;
    }
    cstf(&CP[b*1024 + c], u_b1[c] + ((a0+a1)+(a2+a3)));
  }
  lbar(flags, w, epoch);

  for (int s=0;s<32;s++){
    // CP fixed across the 8 DEQ iters — hoist (sc1; lbar precedes).
    float cpv = (tid < 128) ? cldf(&CP[bA*1024 + cA]) : 0.f;
    for (int i=0;i<8;i++){
      float* zc = Z + (i&1)*16384;      // holds z_i (complete)
      float* zn = Z + ((i&1)^1)*16384;  // holds z_{i-1}; becomes z_{i+1} via delta-fold
      // stage z_i -> LDS (sc1 coherent loads, coalesced)
      #pragma unroll
      for (int k=0;k<8;k++){
        int idx = k*256 + tid;
        zstage[(idx>>9)*520 + (idx&511)] = cldf(&zc[g*2048 + idx]);
      }
      __syncthreads();
      // ---- dotA: tl[r][ci] = tanh(cpv + z_i[r]·W1z[:,w*32+ci])
      if (tid < 128) {
        const float4* wc4 = ldsA + ciA*129;
        const float*  zr  = zstage + rA*520;
        float a0=0,a1=0,a2=0,a3=0;
        #pragma unroll 8
        for (int j=0;j<128;j++){
          float4 wv = wc4[j];
          float4 zv = *(const float4*)(zr + 4*j);
          a0 += zv.x*wv.x; a1 += zv.y*wv.y; a2 += zv.z*wv.z; a3 += zv.w*wv.w;
        }
        tl[rA*36 + ciA] = tanhf(cpv + (a0+a1)+(a2+a3));
      }
      __syncthreads();
      // ---- dotB + delta-fold atomics: each WG adds 0.5*slice + (z_i - z_{i-1} + 0.5b2)/32
      {
        const float* trow = tl + r3*36;
        float accs[8] = {0.f,0.f,0.f,0.f,0.f,0.f,0.f,0.f};
        #pragma unroll
        for (int j4=0;j4<8;j4++){
          float4 tv = *(const float4*)(trow + 4*j4);
          const float4* wrow = ldsB + j4*512 + c2l;
          #pragma unroll
          for (int cc=0;cc<8;cc++){
            float4 wv = wrow[64*cc];
            accs[cc] += tv.x*wv.x + tv.y*wv.y + tv.z*wv.z + tv.w*wv.w;
          }
        }
        float* zrow = &zn[(g*4+r3)*512];
        #pragma unroll
        for (int cc=0;cc<8;cc++){
          int c2 = c2l + 64*cc;
          float zi = zstage[r3*520 + c2];
          float val = 0.5f*accs[cc] + (zi - zp[cc] + bh[cc]) * 0.03125f;
          zp[cc] = zi;
          atomicAdd(&zrow[c2], val);
        }
      }
      if (i==7 && tid>=128) {  // init liquid pre-act buffers with biases (sc1)
        int idx = w*128 + (tid-128);
        if (idx < 2048){ int r=idx>>9, c=idx&511; cstf(&G[(g*4+r)*512+c], l_b[c]); }
        else { int i2=idx-2048; int r=i2>>9, c=i2&511; cstf(&TA[(g*4+r)*512+c], l_bt[c]); }
      }
      lbar(flags, w, epoch);
    }
    // ---- L1: liquid gate/tau pre-activations (v14 verbatim; final z in buffer 0) ----
    #pragma unroll
    for (int k=0;k<8;k++){
      int idx = k*256 + tid; int r = idx>>9, c = idx&511;
      const float* src = (kh==0) ? &Z[g*2048 + idx] : &H[g*2048 + idx];
      zstage[r*520 + c] = cldf(src);
    }
    __syncthreads();
    {
      int sub = tid>>7, l = tid&127;
      int r = l>>5, b = g*4+r;
      int c2 = (w&15)*32 + (l&31);
      const float* inrow = zstage + r*520;
      const float* Wc = (sub ? (kh==0 ? wsF+OF_LWTIT : wsF+OF_LWTHT)
                             : (kh==0 ? wsF+OF_LWIT  : wsF+OF_LWHT)) + (size_t)c2*512;
      float a0=0,a1=0,a2=0,a3=0;
      #pragma unroll 8
      for (int k=0;k<512;k+=4){
        float4 iv = *(const float4*)(inrow + k);
        float4 wv = *(const float4*)(Wc + k);
        a0 += iv.x*wv.x; a1 += iv.y*wv.y; a2 += iv.z*wv.z; a3 += iv.w*wv.w;
      }
      atomicAdd(sub ? &TA[b*512+c2] : &G[b*512+c2], (a0+a1)+(a2+a3));
    }
    lbar(flags, w, epoch);
    // ---- L2: h update (+snapshots at write step) | c_pre for next step (v14 verbatim) ----
    if (w < 16) {
      if (tid < 128) {
        int r = tid>>5, b = g*4+r;
        int c2 = w*32 + (tid&31);
        float gv = tanhf(cldf(&G[b*512+c2]));
        float tv = softplusf_(cldf(&TA[b*512+c2])) + 1.0f;
        float hv = cldf(&H[b*512+c2]);
        float hn = hv + (gv - hv)/tv;
        cstf(&H[b*512+c2], hn);
        if (write_pos[b] == s) {
          cstf(&ZS[b*512+c2], cldf(&Z[b*512+c2]));
          cstf(&HS[b*512+c2], hn);
        }
      }
    } else if (s+1 < 32) {
      int r = tid>>6, b = g*4+r;
      int c = (w-16)*64 + (tid&63);
      int tok = tokens[b*64 + s+1];
      const float* xr = embed_W + (size_t)tok*256;
      const float* wc = wsF + OF_W1XT + (size_t)c*256;
      float a0=0,a1=0,a2=0,a3=0;
      #pragma unroll 4
      for (int k=0;k<256;k+=4){
        float4 xv = *(const float4*)(xr + k);
        float4 wv = *(const float4*)(wc + k);
        a0 += xv.x*wv.x; a1 += xv.y*wv.y; a2 += xv.z*wv.z; a3 += xv.w*wv.w;
      }
      cstf(&CP[b*1024 + c], u_b1[c] + ((a0+a1)+(a2+a3)));
    }
    lbar(flags, w, epoch);
  }
}

// ---------------- kernel 3: v_pred + decay-weighted scatter into M (v14 verbatim) ----------------
__global__ void __launch_bounds__(256) emma_k3(const float* z2v_W, const float* z2v_b,
                                               int* wsI, float* wsF)
{
  const int b = blockIdx.x, c = threadIdx.x;
  const float* zs = wsF + OF_ZS + b*512;
  const float* hs = wsF + OF_HS + b*512;
  float acc = z2v_b[c];
  for (int k=0;k<512;k++) acc += zs[k]*z2v_W[k*256 + c];
  for (int k=0;k<512;k++) acc += hs[k]*z2v_W[(512+k)*256 + c];
  __shared__ float red[256];
  red[c]=acc*acc; __syncthreads();
  for (int st=128; st; st>>=1){ if (c<st) red[c]+=red[c+st]; __syncthreads(); }
  float inv = 1.f/fmaxf(sqrtf(red[0]),1e-12f);
  float vp = acc*inv;
  float f = wsF[OF_DFAC + b];
  for (int j=0;j<16;j++){
    int slot = wsI[2048 + b*16 + j];
    float wj = wsF[OF_TOPW + b*16 + j];
    atomicAdd(&wsF[OF_M + (size_t)slot*256 + c], f*wj*vp);
  }
}

// ---------------- kernel 4: v_mem read, normalize, logits (v14 verbatim) ----------------
__global__ void __launch_bounds__(256) emma_k4(const float* value_W, int* wsI, float* wsF,
                                               float* out)
{
  const int b = blockIdx.x, c = threadIdx.x;
  float m = 0.f;
  for (int j=0;j<16;j++){
    int slot = wsI[2048 + b*16 + j];
    m += wsF[OF_TOPW + b*16 + j] * wsF[OF_M + (size_t)slot*256 + c];
  }
  __shared__ float red[256];
  __shared__ float vn[256];
  red[c]=m*m; __syncthreads();
  for (int st=128; st; st>>=1){ if (c<st) red[c]+=red[c+st]; __syncthreads(); }
  float inv = 1.f/fmaxf(sqrtf(red[0]),1e-12f);
  vn[c] = m*inv;
  __syncthreads();
  float scale = wsF[OF_SCALE];
  for (int q=0;q<4;q++){
    int val = q*256 + c;
    const float* row = value_W + (size_t)val*256;
    float d0=0,d1=0,d2=0,d3=0;
    #pragma unroll 4
    for (int k=0;k<256;k+=4){
      float4 rv = *(const float4*)(row + k);
      d0 += vn[k+0]*rv.x; d1 += vn[k+1]*rv.y; d2 += vn[k+2]*rv.z; d3 += vn[k+3]*rv.w;
    }
    out[b*1024 + val] = scale * wsF[OF_RNV + val] * ((d0+d1)+(d2+d3));
  }
}

extern "C" void kernel_launch(void* const* d_in, const int* in_sizes, int n_in,
                              void* d_out, int out_size, void* d_ws, size_t ws_size,
                              hipStream_t stream)
{
  const int*   tokens    = (const int*)  d_in[0];
  const int*   key_ids   = (const int*)  d_in[1];
  const int*   write_pos = (const int*)  d_in[2];
  const float* embed_W   = (const float*)d_in[5];
  const float* key_W     = (const float*)d_in[6];
  const float* value_W   = (const float*)d_in[7];
  const float* u_W1      = (const float*)d_in[8];
  const float* u_b1      = (const float*)d_in[9];
  const float* u_W2      = (const float*)d_in[10];
  const float* u_b2      = (const float*)d_in[11];
  const float* l_Wi      = (const float*)d_in[12];
  const float* l_Wh      = (const float*)d_in[13];
  const float* l_b       = (const float*)d_in[14];
  const float* l_Wti     = (const float*)d_in[15];
  const float* l_Wth     = (const float*)d_in[16];
  const float* l_bt      = (const float*)d_in[17];
  const float* h0        = (const float*)d_in[18];
  const float* z2v_W     = (const float*)d_in[19];
  const float* z2v_b     = (const float*)d_in[20];
  const float* lsr       = (const float*)d_in[21];
  const float* slot_keys = (const float*)d_in[22];

  int*   wsI = (int*)d_ws;
  float* wsF = (float*)((char*)d_ws + 16384);
  float* out = (float*)d_out;

  hipLaunchKernelGGL(emma_k1a, dim3(325), dim3(256), 0, stream,
                     key_ids, write_pos, key_W, value_W, slot_keys, lsr, wsI, wsF);
  hipLaunchKernelGGL(emma_k1b, dim3(32), dim3(256), 0, stream, wsI, wsF);
  // weight transposes (row-major [R][1<<shift] -> col-major):
  hipLaunchKernelGGL(emma_tr, dim3(512), dim3(256), 0, stream, u_W1,            wsF+OF_W1ZT, 10, 512*1024);
  hipLaunchKernelGGL(emma_tr, dim3(512), dim3(256), 0, stream, u_W1 + 512*1024, wsF+OF_W1XT, 10, 256*1024);
  hipLaunchKernelGGL(emma_tr, dim3(512), dim3(256), 0, stream, u_W2,            wsF+OF_W2T,   9, 1024*512);
  hipLaunchKernelGGL(emma_tr, dim3(512), dim3(256), 0, stream, l_Wi,            wsF+OF_LWIT,  9, 512*512);
  hipLaunchKernelGGL(emma_tr, dim3(512), dim3(256), 0, stream, l_Wh,            wsF+OF_LWHT,  9, 512*512);
  hipLaunchKernelGGL(emma_tr, dim3(512), dim3(256), 0, stream, l_Wti,           wsF+OF_LWTIT, 9, 512*512);
  hipLaunchKernelGGL(emma_tr, dim3(512), dim3(256), 0, stream, l_Wth,           wsF+OF_LWTHT, 9, 512*512);
  {
    void* args[] = { (void*)&tokens, (void*)&write_pos, (void*)&embed_W,
                     (void*)&u_b1, (void*)&u_b2, (void*)&l_b, (void*)&l_bt, (void*)&h0,
                     (void*)&wsI, (void*)&wsF };
    hipLaunchCooperativeKernel(reinterpret_cast<void*>(emma_k2), dim3(256), dim3(256),
                               args, 0, stream);
  }
  hipLaunchKernelGGL(emma_k3, dim3(32), dim3(256), 0, stream, z2v_W, z2v_b, wsI, wsF);
  hipLaunchKernelGGL(emma_k4, dim3(32), dim3(256), 0, stream, value_W, wsI, wsF, out);
}

// Round 8
// 3456.593 us; speedup vs baseline: 3.1656x; 1.0961x over previous
//
#include <hip/hip_runtime.h>
#include <math.h>

// EMMA_38792144617759 v16 — v15 (passed, 3.79ms) with three changes:
// (1) L2 phase DELETED (321->289 lbars): h-update (needs G/TA/H, stable after
//     L1's lbar) and CP(s+1) (static inputs) move into the idle tid>=128 slot
//     during dotA's window at iters 0-1 of the NEXT step; G/TA bias-init moves
//     into the i==7 window. L1(s) still reads H=h_{s-1} (updated iter0(s),
//     barriers between) — order-equivalent to v15. Epilogue covers
//     write_pos==31 snapshots.
// (2) dotB atomics STAGGERED: cc-outer loop with per-WG address rotation
//     ((cco+(w&7))&7 applied to the address; register indices stay static),
//     atomic issued right after each 8-FMA dot -> the 32 WGs' same-address
//     bursts spread over 8 disjoint octaves and over the dotB window,
//     shortening the vmcnt(0) drain (v15 WRITE_SIZE 5x'd to 545MB; drain was
//     on every lbar's critical path).
// (3) tl row hoisted to float4 tvv[8] regs.
// Protocols unchanged: lbar, sc1 data path, double-buffer delta-fold (1/32
// share), ldsA 129-pad, ldsB [j4][c2].

#define NGRP 8
#define WPG  32

// ---- workspace float offsets (wsF = d_ws + 16KB; first 16KB is int region) ----
#define OF_SCALE  0
#define OF_DFAC   32
#define OF_RNV    64
#define OF_TOPW   1088
#define OF_SCORES 1600      // 32*4096
#define OF_Z      132672    // 2*32*512 (double-buffered z)
#define OF_CP     198208    // 32*1024 (global CP)
#define OF_G      230976    // 32*512
#define OF_TAU    247360    // 32*512
#define OF_H      263744    // 32*512
#define OF_ZS     280128    // 32*512
#define OF_HS     296512    // 32*512
#define OF_M      312896    // 4096*256
// transposed weight copies (filled by emma_tr before k2):
#define OF_W1ZT   1361472   // [1024 c][512 k]  = u_W1[k][c], k<512
#define OF_W1XT   1885760   // [1024 c][256 k]  = u_W1[512+k][c]
#define OF_W2T    2147904   // [512 c][1024 k]  = u_W2[k][c]
#define OF_LWIT   2672192   // [512 c][512 k]   = l_Wi[k][c]
#define OF_LWHT   2934336   // [512 c][512 k]   = l_Wh[k][c]
#define OF_LWTIT  3196480   // [512 c][512 k]   = l_Wti[k][c]
#define OF_LWTHT  3458624   // [512 c][512 k]   = l_Wth[k][c]
// wsI: [0..2048) barrier flags region (g*32+w used), [2048..2560) top_i

__device__ __forceinline__ float softplusf_(float x){ return x > 20.f ? x : log1pf(expf(x)); }

__device__ __forceinline__ float cldf(const float* p){
  return __hip_atomic_load(p, __ATOMIC_RELAXED, __HIP_MEMORY_SCOPE_AGENT);
}
__device__ __forceinline__ void cstf(float* p, float v){
  __hip_atomic_store(p, v, __ATOMIC_RELAXED, __HIP_MEMORY_SCOPE_AGENT);
}

// Light fence-free barrier (PROVEN v10/v11/v14/v15): all cross-WG data moves
// via sc1 (LLC) ops; vmcnt(0) drains this wave's sc1 stores/atomics first.
__device__ __forceinline__ void lbar(int* flags, int w, int& epoch){
  asm volatile("s_waitcnt vmcnt(0)" ::: "memory");
  __syncthreads();
  epoch++;
  if (threadIdx.x == 0)
    __hip_atomic_store(&flags[w], epoch, __ATOMIC_RELAXED, __HIP_MEMORY_SCOPE_AGENT);
  if (threadIdx.x < 32){
    while (__hip_atomic_load(&flags[threadIdx.x], __ATOMIC_RELAXED,
                             __HIP_MEMORY_SCOPE_AGENT) < epoch)
      __builtin_amdgcn_s_sleep(1);
  }
  asm volatile("" ::: "memory");
  __syncthreads();
}

// ---------------- kernel 0: generic row-major -> col-major transpose ----------------
__global__ void __launch_bounds__(256) emma_tr(const float* src, float* dst,
                                               int shift, int total)
{
  const int R = total >> shift;
  const int cmask = (1 << shift) - 1;
  for (int idx = blockIdx.x*256 + threadIdx.x; idx < total; idx += gridDim.x*256){
    int r = idx >> shift, c = idx & cmask;
    dst[(size_t)c * R + r] = src[idx];
  }
}

// ---------------- kernel 1a: scores, M zero, value-row norms, misc (v15 verbatim) ----------------
__global__ void __launch_bounds__(256) emma_k1a(
    const int* key_ids, const int* write_pos,
    const float* key_W, const float* value_W, const float* slot_keys,
    const float* lsr, int* wsI, float* wsF)
{
  const int wg = blockIdx.x, tid = threadIdx.x;
  if (wg < 256) {
    const int b = wg >> 3, chunk = wg & 7;
    __shared__ __align__(16) float s_kv[256];
    __shared__ float red[256];
    float v = key_W[key_ids[b]*256 + tid];
    red[tid] = v*v; __syncthreads();
    for (int st=128; st; st>>=1){ if (tid<st) red[tid]+=red[tid+st]; __syncthreads(); }
    float inv = 1.f/fmaxf(sqrtf(red[0]), 1e-12f);
    s_kv[tid] = v*inv;
    __syncthreads();
    const int lane = tid & 63, wv = tid >> 6;
    float4 kv4 = *(const float4*)(s_kv + lane*4);
    for (int slot = chunk*512 + wv; slot < chunk*512 + 512; slot += 4){
      float4 sk = *(const float4*)(slot_keys + (size_t)slot*256 + lane*4);
      float p = kv4.x*sk.x + kv4.y*sk.y + kv4.z*sk.z + kv4.w*sk.w;
      #pragma unroll
      for (int m=32;m;m>>=1) p += __shfl_xor(p, m, 64);
      if (lane==0) wsF[OF_SCORES + b*4096 + slot] = p;
    }
  } else if (wg < 320) {
    const int j = wg - 256;
    for (int i=tid;i<16384;i+=256) wsF[OF_M + j*16384 + i] = 0.f;
  } else if (wg < 324) {
    const int row = (wg-320)*256 + tid;
    float ss=0.f; const float* r = value_W + (size_t)row*256;
    for (int k=0;k<256;k++){ float x=r[k]; ss += x*x; }
    wsF[OF_RNV + row] = 1.f/fmaxf(sqrtf(ss), 1e-12f);
  } else {
    for (int i=tid;i<2048;i+=256) wsI[i]=0;
    __shared__ int pres[32];
    if (tid<32){ int p=0; for (int bb=0;bb<32;bb++) if (write_pos[bb]==tid) p=1; pres[tid]=p; }
    __syncthreads();
    if (tid<32){
      int wp = write_pos[tid]; float f=1.f;
      for (int s=wp+1;s<32;s++) if (pres[s]) f *= 0.997f;
      wsF[OF_DFAC + tid] = f;
    }
    if (tid==0) wsF[OF_SCALE] = softplusf_(lsr[0]) + 1e-3f;
  }
}

// ---------------- kernel 1b: exact top-16 + softmax (v15 verbatim) ----------------
__global__ void __launch_bounds__(256) emma_k1b(int* wsI, float* wsF)
{
  const int b = blockIdx.x, tid = threadIdx.x;
  __shared__ float s_sc[4096];
  __shared__ float s_rv[256]; __shared__ int s_ri[256];
  __shared__ float s_tv[16];
  for (int n=tid;n<4096;n+=256) s_sc[n] = wsF[OF_SCORES + b*4096 + n];
  __syncthreads();
  for (int j=0;j<16;j++){
    float bv = -3.0e38f; int bi = 0x7fffffff;
    for (int n=tid;n<4096;n+=256){
      float v = s_sc[n];
      if (v > bv || (v == bv && n < bi)) { bv=v; bi=n; }
    }
    s_rv[tid]=bv; s_ri[tid]=bi; __syncthreads();
    for (int st=128; st; st>>=1){
      if (tid<st){
        float v2=s_rv[tid+st]; int i2=s_ri[tid+st];
        if (v2 > s_rv[tid] || (v2==s_rv[tid] && i2 < s_ri[tid])) { s_rv[tid]=v2; s_ri[tid]=i2; }
      }
      __syncthreads();
    }
    if (tid==0){
      s_tv[j] = s_rv[0];
      wsI[2048 + b*16 + j] = s_ri[0];
      s_sc[s_ri[0]] = -3.0e38f;
    }
    __syncthreads();
  }
  if (tid==0){
    float mx = s_tv[0], sum=0.f, w[16];
    for (int j=0;j<16;j++){ w[j]=expf(s_tv[j]-mx); sum+=w[j]; }
    for (int j=0;j<16;j++) wsF[OF_TOPW + b*16 + j] = w[j]/sum;
  }
}

// ---------------- kernel 2: persistent trajectory (9 phases/step; window-absorbed L2) ----------------
__global__ void __launch_bounds__(256, 1) emma_k2(
    const int* tokens, const int* write_pos,
    const float* embed_W, const float* u_b1, const float* u_b2,
    const float* l_b, const float* l_bt, const float* h0,
    int* wsI, float* wsF)
{
  const int g = blockIdx.x & 7;
  const int w = blockIdx.x >> 3;
  const int tid = threadIdx.x;
  int* flags = wsI + g*32;
  int epoch = 0;

  float* Z  = wsF + OF_Z;
  float* CP = wsF + OF_CP;
  float* G  = wsF + OF_G;
  float* TA = wsF + OF_TAU;
  float* H  = wsF + OF_H;
  float* ZS = wsF + OF_ZS;
  float* HS = wsF + OF_HS;

  __shared__ __align__(16) float4 ldsA[32*129];   // W1ZT cols [w*32,+32), 129-f4 pad
  __shared__ __align__(16) float4 ldsB[4096];     // W2 [j4][c2]: rows k in [w*32,+32)
  __shared__ __align__(16) float zstage[4*520];   // group activations [4][520-pad]
  __shared__ __align__(16) float tl[4*36];        // T tile [4 rows][32 local cols, pad 36]

  // ---- stage per-WG weight slices into LDS (once) ----
  {
    const float* gA = wsF + OF_W1ZT + (size_t)(w*32)*512;
    const float* gB = wsF + OF_W2T;
    for (int idx4 = tid; idx4 < 4096; idx4 += 256){
      { int ci = idx4 >> 7, j = idx4 & 127;
        ldsA[ci*129 + j] = *(const float4*)(gA + (size_t)ci*512 + 4*j); }
      { int j4 = idx4 >> 9, c2 = idx4 & 511;   // dst = j4*512 + c2 = idx4
        ldsB[idx4] = *(const float4*)(gB + (size_t)c2*1024 + w*32 + 4*j4); }
    }
  }

  // per-thread loop-invariant constants
  const int rA  = tid >> 5;            // valid for tid<128 phases
  const int bA  = g*4 + (rA & 3);
  const int ciA = tid & 31;
  const int cA  = w*32 + ciA;          // dotA output col (global k index)
  const int r3  = tid >> 6;            // dotB row
  const int c2l = tid & 63;            // dotB col residue
  const int rot = w & 7;               // atomic stagger rotation
  const int kh  = w >> 4;              // L1 k-half
  float bh[8];                         // 0.5*b2 for this thread's 8 c2 (rotated map)
  #pragma unroll
  for (int cco=0;cco<8;cco++){
    int cc = (cco + rot) & 7;
    bh[cco] = 0.5f*u_b2[c2l + (cc<<6)];
  }
  float zp[8] = {0.f,0.f,0.f,0.f,0.f,0.f,0.f,0.f};   // z_{i-1} carry (z_{-1}=0)

  // ---- preamble: z bufs 0 AND 1 = 0, h=h0 | c_pre for step 0 (v15 verbatim) ----
  if (w < 16) {
    int idx = w*256 + tid;
    if (idx < 2048) cstf(&Z[g*2048 + idx], 0.f);
    else { int i2=idx-2048; int r=i2>>9, c=i2&511; cstf(&H[(g*4+r)*512 + c], h0[c]); }
  } else {
    { int idx = (w-16)*256 + tid;
      if (idx < 2048) cstf(&Z[16384 + g*2048 + idx], 0.f); }
    int r = tid>>6, b = g*4+r;
    int c = (w-16)*64 + (tid&63);
    int tok = tokens[b*64 + 0];
    const float* xr = embed_W + (size_t)tok*256;
    const float* wc = wsF + OF_W1XT + (size_t)c*256;
    float a0=0,a1=0,a2=0,a3=0;
    #pragma unroll 4
    for (int k=0;k<256;k+=4){
      float4 xv = *(const float4*)(xr + k);
      float4 wv = *(const float4*)(wc + k);
      a0 += xv.x*wv.x; a1 += xv.y*wv.y; a2 += xv.z*wv.z; a3 += xv.w*wv.w;
    }
    cstf(&CP[b*1024 + c], u_b1[c] + ((a0+a1)+(a2+a3)));
  }
  lbar(flags, w, epoch);

  for (int s=0;s<32;s++){
    // CP fixed across the 8 DEQ iters — hoist (sc1; lbar precedes).
    float cpv = (tid < 128) ? cldf(&CP[bA*1024 + cA]) : 0.f;
    for (int i=0;i<8;i++){
      float* zc = Z + (i&1)*16384;      // holds z_i (complete)
      float* zn = Z + ((i&1)^1)*16384;  // holds z_{i-1}; becomes z_{i+1} via delta-fold
      // stage z_i -> LDS (sc1 coherent loads, coalesced)
      #pragma unroll
      for (int k=0;k<8;k++){
        int idx = k*256 + tid;
        zstage[(idx>>9)*520 + (idx&511)] = cldf(&zc[g*2048 + idx]);
      }
      __syncthreads();
      // ---- dotA (tid<128) ∥ window tasks (tid>=128: h-update / CP / G-TA init)
      if (tid < 128) {
        const float4* wc4 = ldsA + ciA*129;
        const float*  zr  = zstage + rA*520;
        float a0=0,a1=0,a2=0,a3=0;
        #pragma unroll 8
        for (int j=0;j<128;j++){
          float4 wv = wc4[j];
          float4 zv = *(const float4*)(zr + 4*j);
          a0 += zv.x*wv.x; a1 += zv.y*wv.y; a2 += zv.z*wv.z; a3 += zv.w*wv.w;
        }
        tl[rA*36 + ciA] = tanhf(cpv + (a0+a1)+(a2+a3));
      } else {
        if (i == 0 && w < 16 && s >= 1) {
          // h-update for step s-1 (G/TA complete after L1(s-1) lbar) + snapshots
          int idx = w*128 + (tid-128);
          int r = idx>>9, c2 = idx&511, b = g*4+r;
          float gv = tanhf(cldf(&G[b*512+c2]));
          float tv = softplusf_(cldf(&TA[b*512+c2])) + 1.0f;
          float hv = cldf(&H[b*512+c2]);
          float hn = hv + (gv - hv)/tv;
          cstf(&H[b*512+c2], hn);
          if (write_pos[b] == s-1) {
            cstf(&ZS[b*512+c2], zstage[r*520 + c2]);   // z final of step s-1
            cstf(&HS[b*512+c2], hn);
          }
        } else if (i <= 1 && w >= 16 && s+1 < 32) {
          // CP for step s+1 (static inputs), half per iter
          int e = i*2048 + (w-16)*128 + (tid-128);
          int r = e>>10, c = e&1023, b = g*4+r;
          int tok = tokens[b*64 + s+1];
          const float* xr = embed_W + (size_t)tok*256;
          const float* wc = wsF + OF_W1XT + (size_t)c*256;
          float a0=0,a1=0,a2=0,a3=0;
          #pragma unroll 4
          for (int k=0;k<256;k+=4){
            float4 xv = *(const float4*)(xr + k);
            float4 wv = *(const float4*)(wc + k);
            a0 += xv.x*wv.x; a1 += xv.y*wv.y; a2 += xv.z*wv.z; a3 += xv.w*wv.w;
          }
          cstf(&CP[b*1024 + c], u_b1[c] + ((a0+a1)+(a2+a3)));
        } else if (i == 7) {
          // init liquid pre-act buffers with biases for L1(s)
          int idx = w*128 + (tid-128);
          if (idx < 2048){ int r=idx>>9, c=idx&511; cstf(&G[(g*4+r)*512+c], l_b[c]); }
          else { int i2=idx-2048; int r=i2>>9, c=i2&511; cstf(&TA[(g*4+r)*512+c], l_bt[c]); }
        }
      }
      __syncthreads();
      // ---- dotB + delta-fold atomics, cc-outer STAGGERED by (w&7)
      {
        const float* trow = tl + r3*36;
        float4 tvv[8];
        #pragma unroll
        for (int j4=0;j4<8;j4++) tvv[j4] = *(const float4*)(trow + 4*j4);
        float* zrow = &zn[(g*4+r3)*512];
        #pragma unroll
        for (int cco=0;cco<8;cco++){
          int cc = (cco + rot) & 7;            // address rotation only
          int c2 = c2l + (cc<<6);
          const float4* wrow = ldsB + c2;
          float acc = 0.f;
          #pragma unroll
          for (int j4=0;j4<8;j4++){
            float4 wv = wrow[j4*512];
            float4 tv = tvv[j4];
            acc += tv.x*wv.x + tv.y*wv.y + tv.z*wv.z + tv.w*wv.w;
          }
          float zi = zstage[r3*520 + c2];
          float val = 0.5f*acc + (zi - zp[cco] + bh[cco]) * 0.03125f;
          zp[cco] = zi;
          atomicAdd(&zrow[c2], val);
        }
      }
      lbar(flags, w, epoch);
    }
    // ---- L1: liquid gate/tau pre-activations (final z in buffer 0) ----
    #pragma unroll
    for (int k=0;k<8;k++){
      int idx = k*256 + tid; int r = idx>>9, c = idx&511;
      const float* src = (kh==0) ? &Z[g*2048 + idx] : &H[g*2048 + idx];
      zstage[r*520 + c] = cldf(src);
    }
    __syncthreads();
    {
      int sub = tid>>7, l = tid&127;
      int r = l>>5, b = g*4+r;
      int c2 = (w&15)*32 + (l&31);
      const float* inrow = zstage + r*520;
      const float* Wc = (sub ? (kh==0 ? wsF+OF_LWTIT : wsF+OF_LWTHT)
                             : (kh==0 ? wsF+OF_LWIT  : wsF+OF_LWHT)) + (size_t)c2*512;
      float a0=0,a1=0,a2=0,a3=0;
      #pragma unroll 8
      for (int k=0;k<512;k+=4){
        float4 iv = *(const float4*)(inrow + k);
        float4 wv = *(const float4*)(Wc + k);
        a0 += iv.x*wv.x; a1 += iv.y*wv.y; a2 += iv.z*wv.z; a3 += iv.w*wv.w;
      }
      atomicAdd(sub ? &TA[b*512+c2] : &G[b*512+c2], (a0+a1)+(a2+a3));
    }
    lbar(flags, w, epoch);
  }
  // ---- epilogue: h-update for s=31 + snapshots (no further barrier needed;
  // kernel boundary orders ZS/HS for k3) ----
  if (w < 16 && tid >= 128) {
    int idx = w*128 + (tid-128);
    int r = idx>>9, c2 = idx&511, b = g*4+r;
    float gv = tanhf(cldf(&G[b*512+c2]));
    float tv = softplusf_(cldf(&TA[b*512+c2])) + 1.0f;
    float hv = cldf(&H[b*512+c2]);
    float hn = hv + (gv - hv)/tv;
    if (write_pos[b] == 31) {
      cstf(&ZS[b*512+c2], cldf(&Z[b*512+c2]));   // buf0 = final z(31)
      cstf(&HS[b*512+c2], hn);
    }
  }
}

// ---------------- kernel 3: v_pred + decay-weighted scatter into M (v15 verbatim) ----------------
__global__ void __launch_bounds__(256) emma_k3(const float* z2v_W, const float* z2v_b,
                                               int* wsI, float* wsF)
{
  const int b = blockIdx.x, c = threadIdx.x;
  const float* zs = wsF + OF_ZS + b*512;
  const float* hs = wsF + OF_HS + b*512;
  float acc = z2v_b[c];
  for (int k=0;k<512;k++) acc += zs[k]*z2v_W[k*256 + c];
  for (int k=0;k<512;k++) acc += hs[k]*z2v_W[(512+k)*256 + c];
  __shared__ float red[256];
  red[c]=acc*acc; __syncthreads();
  for (int st=128; st; st>>=1){ if (c<st) red[c]+=red[c+st]; __syncthreads(); }
  float inv = 1.f/fmaxf(sqrtf(red[0]),1e-12f);
  float vp = acc*inv;
  float f = wsF[OF_DFAC + b];
  for (int j=0;j<16;j++){
    int slot = wsI[2048 + b*16 + j];
    float wj = wsF[OF_TOPW + b*16 + j];
    atomicAdd(&wsF[OF_M + (size_t)slot*256 + c], f*wj*vp);
  }
}

// ---------------- kernel 4: v_mem read, normalize, logits (v15 verbatim) ----------------
__global__ void __launch_bounds__(256) emma_k4(const float* value_W, int* wsI, float* wsF,
                                               float* out)
{
  const int b = blockIdx.x, c = threadIdx.x;
  float m = 0.f;
  for (int j=0;j<16;j++){
    int slot = wsI[2048 + b*16 + j];
    m += wsF[OF_TOPW + b*16 + j] * wsF[OF_M + (size_t)slot*256 + c];
  }
  __shared__ float red[256];
  __shared__ float vn[256];
  red[c]=m*m; __syncthreads();
  for (int st=128; st; st>>=1){ if (c<st) red[c]+=red[c+st]; __syncthreads(); }
  float inv = 1.f/fmaxf(sqrtf(red[0]),1e-12f);
  vn[c] = m*inv;
  __syncthreads();
  float scale = wsF[OF_SCALE];
  for (int q=0;q<4;q++){
    int val = q*256 + c;
    const float* row = value_W + (size_t)val*256;
    float d0=0,d1=0,d2=0,d3=0;
    #pragma unroll 4
    for (int k=0;k<256;k+=4){
      float4 rv = *(const float4*)(row + k);
      d0 += vn[k+0]*rv.x; d1 += vn[k+1]*rv.y; d2 += vn[k+2]*rv.z; d3 += vn[k+3]*rv.w;
    }
    out[b*1024 + val] = scale * wsF[OF_RNV + val] * ((d0+d1)+(d2+d3));
  }
}

extern "C" void kernel_launch(void* const* d_in, const int* in_sizes, int n_in,
                              void* d_out, int out_size, void* d_ws, size_t ws_size,
                              hipStream_t stream)
{
  const int*   tokens    = (const int*)  d_in[0];
  const int*   key_ids   = (const int*)  d_in[1];
  const int*   write_pos = (const int*)  d_in[2];
  const float* embed_W   = (const float*)d_in[5];
  const float* key_W     = (const float*)d_in[6];
  const float* value_W   = (const float*)d_in[7];
  const float* u_W1      = (const float*)d_in[8];
  const float* u_b1      = (const float*)d_in[9];
  const float* u_W2      = (const float*)d_in[10];
  const float* u_b2      = (const float*)d_in[11];
  const float* l_Wi      = (const float*)d_in[12];
  const float* l_Wh      = (const float*)d_in[13];
  const float* l_b       = (const float*)d_in[14];
  const float* l_Wti     = (const float*)d_in[15];
  const float* l_Wth     = (const float*)d_in[16];
  const float* l_bt      = (const float*)d_in[17];
  const float* h0        = (const float*)d_in[18];
  const float* z2v_W     = (const float*)d_in[19];
  const float* z2v_b     = (const float*)d_in[20];
  const float* lsr       = (const float*)d_in[21];
  const float* slot_keys = (const float*)d_in[22];

  int*   wsI = (int*)d_ws;
  float* wsF = (float*)((char*)d_ws + 16384);
  float* out = (float*)d_out;

  hipLaunchKernelGGL(emma_k1a, dim3(325), dim3(256), 0, stream,
                     key_ids, write_pos, key_W, value_W, slot_keys, lsr, wsI, wsF);
  hipLaunchKernelGGL(emma_k1b, dim3(32), dim3(256), 0, stream, wsI, wsF);
  // weight transposes (row-major [R][1<<shift] -> col-major):
  hipLaunchKernelGGL(emma_tr, dim3(512), dim3(256), 0, stream, u_W1,            wsF+OF_W1ZT, 10, 512*1024);
  hipLaunchKernelGGL(emma_tr, dim3(512), dim3(256), 0, stream, u_W1 + 512*1024, wsF+OF_W1XT, 10, 256*1024);
  hipLaunchKernelGGL(emma_tr, dim3(512), dim3(256), 0, stream, u_W2,            wsF+OF_W2T,   9, 1024*512);
  hipLaunchKernelGGL(emma_tr, dim3(512), dim3(256), 0, stream, l_Wi,            wsF+OF_LWIT,  9, 512*512);
  hipLaunchKernelGGL(emma_tr, dim3(512), dim3(256), 0, stream, l_Wh,            wsF+OF_LWHT,  9, 512*512);
  hipLaunchKernelGGL(emma_tr, dim3(512), dim3(256), 0, stream, l_Wti,           wsF+OF_LWTIT, 9, 512*512);
  hipLaunchKernelGGL(emma_tr, dim3(512), dim3(256), 0, stream, l_Wth,           wsF+OF_LWTHT, 9, 512*512);
  {
    void* args[] = { (void*)&tokens, (void*)&write_pos, (void*)&embed_W,
                     (void*)&u_b1, (void*)&u_b2, (void*)&l_b, (void*)&l_bt, (void*)&h0,
                     (void*)&wsI, (void*)&wsF };
    hipLaunchCooperativeKernel(reinterpret_cast<void*>(emma_k2), dim3(256), dim3(256),
                               args, 0, stream);
  }
  hipLaunchKernelGGL(emma_k3, dim3(32), dim3(256), 0, stream, z2v_W, z2v_b, wsI, wsF);
  hipLaunchKernelGGL(emma_k4, dim3(32), dim3(256), 0, stream, value_W, wsI, wsF, out);
}